// Round 5
// baseline (655.387 us; speedup 1.0000x reference)
//
#include <hip/hip_runtime.h>
#include <stdint.h>

typedef unsigned long long u64;
typedef unsigned int u32;

#define NND 20000      // nodes
#define EUA 160000     // directed input edges (2 * E_UND)
#define EFE 80000      // max clean (undirected, deduped) edges
#define ICH 128
#define HIDC 64
#define SCAN_BS 256
#define NSCAN_B ((NND + SCAN_BS - 1) / SCAN_BS)   // 79
#define PRE_N (NSCAN_B + 1)                       // 80
#define GEB 64         // edges per gemm tile
#define XS_PAD 132     // xs leading-dim pad
#define BK64 64        // fixed bucket stride (degrees Poisson(4/8), max ~25)
#define SEL_BINS 4096  // 12-bit digits, 4 passes (keys: bit48==1 always)
#define FBLK 512       // persistent grid: 2 blocks/CU on 256 CUs (all resident)
#define CHAINS 4096    // moment-reduction chains (MUST stay 4096: bitwise-
                       // identical summation order vs the verified baseline)
#define VMAX ((EFE + CHAINS - 1) / CHAINS)  // 20 edges/chain -> registers

// ---------------- agent-coherent (MALL) access helpers ----------------------
// sc1 stores complete at the Infinity Cache (cross-XCD coherence point) -> no
// wbl2/inv fences ever. Reads stay plain+cached; every communicated array is
// first plain-read only AFTER its sc1 writes completed (first-touch = fresh),
// and no buffer is re-written after having been plain-read (no stale lines).
__device__ __forceinline__ int devLoadI(const int* p) {
    return __hip_atomic_load(p, __ATOMIC_RELAXED, __HIP_MEMORY_SCOPE_AGENT);
}
__device__ __forceinline__ void devStoreI(int* p, int v) {
    __hip_atomic_store(p, v, __ATOMIC_RELAXED, __HIP_MEMORY_SCOPE_AGENT);
}
__device__ __forceinline__ void devStoreF(float* p, float v) {
    __hip_atomic_store(p, v, __ATOMIC_RELAXED, __HIP_MEMORY_SCOPE_AGENT);
}
__device__ __forceinline__ void devStoreU64(u64* p, u64 v) {
    __hip_atomic_store(p, v, __ATOMIC_RELAXED, __HIP_MEMORY_SCOPE_AGENT);
}
__device__ __forceinline__ void devStoreF4(float* p, float a0, float a1,
                                           float a2, float a3) {
    u64 w0 = ((u64)__float_as_uint(a1) << 32) | __float_as_uint(a0);
    u64 w1 = ((u64)__float_as_uint(a3) << 32) | __float_as_uint(a2);
    __hip_atomic_store((u64*)p, w0, __ATOMIC_RELAXED, __HIP_MEMORY_SCOPE_AGENT);
    __hip_atomic_store(((u64*)p) + 1, w1, __ATOMIC_RELAXED, __HIP_MEMORY_SCOPE_AGENT);
}

// ---------------- flat sense barrier (packed slots, no master) --------------
// Each block sc1-stores its monotonically-increasing target to slots[b]
// (packed: 512 ints = 16 lines). All 256 threads sweep 2 slots each and exit
// when everyone arrived. One MALL hop to publish + one to observe.
__device__ __forceinline__ void gsync(int* slots, int b, int tgt) {
    asm volatile("s_waitcnt vmcnt(0)" ::: "memory");
    __syncthreads();
    if (threadIdx.x == 0) devStoreI(slots + b, tgt);
    int i0 = threadIdx.x * 2;
    for (;;) {
        int v0 = (i0 == b) ? tgt : devLoadI(slots + i0);
        int v1 = (i0 + 1 == b) ? tgt : devLoadI(slots + i0 + 1);
        if (__syncthreads_and((v0 >= tgt) && (v1 >= tgt))) break;
        __builtin_amdgcn_s_sleep(1);
    }
    asm volatile("" ::: "memory");
}

// ---------------- LDS union (max member = GEMM 66.5 KB) ---------------------
union ShU {
    struct { float W1s[ICH][HIDC]; float xs[GEB][XS_PAD]; } g;        // 66.5KB
    struct { int shHist[SEL_BINS]; int aux[256]; int shTmp[2];
             int shS[SCAN_BS]; int preA[PRE_N]; int preB[PRE_N];
             int preC[PRE_N]; } m;                                    // ~19KB
    struct { float ring[2][128][HIDC]; int doneCnt[2]; int freeTok[2]; } r; // 64KB
};

struct FParams {
    // inputs
    const int* ei; const float* x; const float* W1; const float* b1;
    const float* gamma1; const float* beta1; const float* W2; const float* b2;
    const int* batch;
    // scratch
    int* cnt; int* bucketV; int* bucketS; int* ucnt; int* uoff; int* bsumsH;
    int* eU; int* eV; int* icnt; int* itmp; int* ilist; int* ilistS;
    float* dinv; float* h; float* Snode; float* partial; float* partial2;
    float* miniP; float* z; float* S2; float* score;
    u64* okey; u64* minOkey; int* hist;
    int* n2c; int* present; int* csize; int* cmemb;
    int* o2n; int* ni; int* ecnt2; int* etmp2; int* eoff2;
    int* uecnt; int* ueoff; int* bkD; int* bkD2;
    int* bsumsA; int* bsumsB; int* bsumsC;
    float* dout; int* slots;
};

// in-kernel exclusive scan, phase A (blocks 0..78); consumers rebuild the
// 79-entry block prefix in LDS (integer-exact == baseline scanA+scanB).
__device__ __forceinline__ void scanAPhase(const int* in, int* rawOut, int* bsums,
                                           int b, int t, int* shS) {
    if (b >= NSCAN_B) return;            // block-uniform branch
    int i = b * SCAN_BS + t;
    int v = (i < NND) ? in[i] : 0;
    shS[t] = v;
    __syncthreads();
    for (int o = 1; o < SCAN_BS; o <<= 1) {
        int tv = (t >= o) ? shS[t - o] : 0;
        __syncthreads();
        shS[t] += tv;
        __syncthreads();
    }
    if (i <= NND) devStoreI(rawOut + i, shS[t] - v);
    if (t == SCAN_BS - 1) devStoreI(bsums + b, shS[t]);
}
__device__ __forceinline__ void buildPre(const int* bsums, int* pre, int t) {
    if (t < NSCAN_B) pre[t + 1] = bsums[t];
    if (t == 0) pre[0] = 0;
    __syncthreads();
    if (t == 0)
        for (int k = 1; k <= NSCAN_B; k++) pre[k] += pre[k - 1];
    __syncthreads();
}
__device__ __forceinline__ int scanAt(const int* raw, const int* pre, int i) {
    return raw[i] + pre[i >> 8];         // valid for 0 <= i <= NND
}

// one radix-select q-step (12 bits); carried (pref, kr) across phases makes
// the baseline's full replay unnecessary -- integer-identical results.
__device__ __forceinline__ void selStep(const int* hq, int t, int* aux, int* shTmp,
                                        u64& pref, int& kr, int shift) {
    int b16[16]; int g = 0;
#pragma unroll
    for (int j = 0; j < 16; j++) { b16[j] = hq[16 * t + j]; g += b16[j]; }
    aux[t] = g;
    __syncthreads();
    for (int o = 1; o < 256; o <<= 1) {
        int v = (t + o < 256) ? aux[t + o] : 0;
        __syncthreads();
        aux[t] += v;
        __syncthreads();
    }
    int suf = aux[t] - g;
    if (suf < kr && kr <= suf + g) {
        int cum = suf, found = 16 * t;
        for (int j = 15; j >= 0; j--) {
            int hc = b16[j];
            if (cum + hc >= kr) { found = 16 * t + j; break; }
            cum += hc;
        }
        shTmp[0] = found;
        shTmp[1] = kr - cum;
    }
    __syncthreads();
    pref |= ((u64)shTmp[0]) << shift;
    kr = shTmp[1];
    __syncthreads();
}

// wave-parallel rank sort over stride-64 buckets (grid-stride, 4 waves/block)
__device__ __forceinline__ void rs64Phase(const int* in, int* out,
                                          const int* lenA, int* ucnt,
                                          int b, int w, int c) {
    for (int a = b * 4 + w; a < NND; a += FBLK * 4) {
        int len = lenA[a];
        int base = a << 6;
        for (int j = c; j < len; j += 64) {
            int v = in[base + j];
            int r = 0;
            for (int i = 0; i < len; i++) {
                int wv = in[base + i];
                r += (wv < v) || (wv == v && i < j);
            }
            devStoreI(out + base + r, v);
        }
        asm volatile("s_waitcnt vmcnt(0)" ::: "memory");
        int cc = 0;
        for (int j = c; j < len; j += 64)
            cc += (j == 0) || (out[base + j] != out[base + j - 1]);
#pragma unroll
        for (int o = 32; o > 0; o >>= 1) cc += __shfl_down(cc, o, 64);
        if (c == 0) devStoreI(ucnt + a, cc);
    }
}

__global__ __launch_bounds__(256, 2) void kFusedAll(FParams P) {
    __shared__ ShU sh;
    int t = threadIdx.x;
    int b = blockIdx.x;
    int gtid = b * 256 + t;
    int w = t >> 6, c = t & 63;
    int ph = 1;
    int E = 0;
#define GSYNC() do { gsync(P.slots, b, ph); ph++; } while (0)

    // ======== HEAD (was 8 dispatches) ========
    // ---- C1: filter (s<d) -> stride-64 buckets ----
    for (int i = gtid; i < EUA; i += FBLK * 256) {
        int s = P.ei[i], d = P.ei[EUA + i];
        if (s < d) {
            int p = atomicAdd(&P.cnt[s], 1);
            devStoreI(P.bucketV + (s << 6) + p, d);
        }
    }
    GSYNC();

    // ---- C2: rank-sort buckets + unique count ----
    rs64Phase(P.bucketV, P.bucketS, P.cnt, P.ucnt, b, w, c);
    GSYNC();

    // ---- C3: scanA(ucnt) -> uoffRaw, bsumsH ----
    scanAPhase(P.ucnt, P.uoff, P.bsumsH, b, t, sh.m.shS);
    GSYNC();

    // ---- C4: compact + incidence count; E becomes register-carried ----
    buildPre(P.bsumsH, sh.m.preA, t);
    E = sh.m.preA[NSCAN_B];
    if (gtid < NND) {
        int u = gtid;
        int s = u << 6, e = s + P.cnt[u];
        int o = scanAt(P.uoff, sh.m.preA, u);
        int myc = 0;
        for (int i = s; i < e; i++)
            if (i == s || P.bucketS[i] != P.bucketS[i - 1]) {
                devStoreI(P.eU + o, u);
                devStoreI(P.eV + o, P.bucketS[i]);
                o++;
                atomicAdd(&P.icnt[P.bucketS[i]], 1);
                myc++;
            }
        if (myc) atomicAdd(&P.icnt[u], myc);
    }
    GSYNC();

    // ---- C5: incidence scatter + dinv ----
    if (gtid < E) {
        int u = P.eU[gtid], v = P.eV[gtid];
        devStoreI(P.ilist + (u << 6) + atomicAdd(&P.itmp[u], 1), gtid);
        devStoreI(P.ilist + (v << 6) + atomicAdd(&P.itmp[v], 1), gtid);
        devStoreF(P.dinv + gtid, rsqrtf((float)(P.icnt[u] + P.icnt[v] - 1)));
    }
    GSYNC();

    // ---- C6: GEMM h = (0.5*(x[u]+x[v])) @ W1  +  rank-sort(ilist) ----
    {
        const float4* Wv = (const float4*)P.W1;
        float4* Ws = (float4*)&sh.g.W1s[0][0];
        for (int i = t; i < ICH * HIDC / 4; i += 256) Ws[i] = Wv[i];
        int nTiles = (E + GEB - 1) / GEB;
        for (int tile = b; tile < nTiles; tile += FBLK) {
            int e0 = tile * GEB;
            __syncthreads();
            {
                int eb = t >> 2, q = t & 3;
                int e = e0 + eb;
                if (e < E) {
                    int u = P.eU[e], v = P.eV[e];
                    const float4* xu = (const float4*)(P.x + (size_t)u * ICH) + q * 8;
                    const float4* xv = (const float4*)(P.x + (size_t)v * ICH) + q * 8;
                    float* xd = &sh.g.xs[eb][q * 32];
#pragma unroll
                    for (int i = 0; i < 8; i++) {
                        float4 a = xu[i], bb = xv[i];
                        xd[i * 4 + 0] = 0.5f * (a.x + bb.x);
                        xd[i * 4 + 1] = 0.5f * (a.y + bb.y);
                        xd[i * 4 + 2] = 0.5f * (a.z + bb.z);
                        xd[i * 4 + 3] = 0.5f * (a.w + bb.w);
                    }
                }
            }
            __syncthreads();
            int cg4 = (t & 15) * 4;
            int es = t >> 4;
            float a00=0,a01=0,a02=0,a03=0, a10=0,a11=0,a12=0,a13=0;
            float a20=0,a21=0,a22=0,a23=0, a30=0,a31=0,a32=0,a33=0;
#pragma unroll 4
            for (int k = 0; k < ICH; k++) {
                float4 wv = *(const float4*)&sh.g.W1s[k][cg4];
                float x0 = sh.g.xs[es][k],      x1 = sh.g.xs[es + 16][k];
                float x2 = sh.g.xs[es + 32][k], x3 = sh.g.xs[es + 48][k];
                a00 += x0*wv.x; a01 += x0*wv.y; a02 += x0*wv.z; a03 += x0*wv.w;
                a10 += x1*wv.x; a11 += x1*wv.y; a12 += x1*wv.z; a13 += x1*wv.w;
                a20 += x2*wv.x; a21 += x2*wv.y; a22 += x2*wv.z; a23 += x2*wv.w;
                a30 += x3*wv.x; a31 += x3*wv.y; a32 += x3*wv.z; a33 += x3*wv.w;
            }
            int e;
            e = e0 + es;      if (e < E) devStoreF4(&P.h[(size_t)e*HIDC + cg4], a00,a01,a02,a03);
            e = e0 + es + 16; if (e < E) devStoreF4(&P.h[(size_t)e*HIDC + cg4], a10,a11,a12,a13);
            e = e0 + es + 32; if (e < E) devStoreF4(&P.h[(size_t)e*HIDC + cg4], a20,a21,a22,a23);
            e = e0 + es + 48; if (e < E) devStoreF4(&P.h[(size_t)e*HIDC + cg4], a30,a31,a32,a33);
        }
    }
    rs64Phase(P.ilist, P.ilistS, P.icnt, P.ucnt, b, w, c);  // ucnt = dummy
    GSYNC();

    // ======== MID-CHAIN ========
    // ---- phase 0: Snode[n][c] (== kSGather) ----
    for (int id = gtid; id < NND * HIDC; id += FBLK * 256) {
        int n = id >> 6;
        int base = n << 6, len = P.icnt[n];
        float acc = 0.f;
        for (int j = 0; j < len; j++) {
            int ed = P.ilistS[base + j];
            acc += P.h[(size_t)ed * HIDC + c] * P.dinv[ed];
        }
        devStoreF(P.Snode + id, acc);
    }
    GSYNC();

    // ---- phase 1: conv1 epilogue in regs + per-chain moments ----
    int gw = b * 4 + w;
    int cA = 2 * gw, cB = cA + 1;
    float vA[VMAX], vB[VMAX];
    {
        float bc = P.b1[c];
        float accA = 0.f, acc2A = 0.f, accB = 0.f, acc2B = 0.f;
#pragma unroll
        for (int it = 0; it < VMAX; it++) {
            int eA = cA + it * CHAINS;
            if (eA < E) {
                float a = P.dinv[eA];
                float val = a * (P.Snode[(size_t)P.eU[eA] * HIDC + c] +
                                 P.Snode[(size_t)P.eV[eA] * HIDC + c]) -
                            a * a * P.h[(size_t)eA * HIDC + c] + bc;
                vA[it] = val; accA += val; acc2A += val * val;
            } else vA[it] = 0.f;
            int eB = cB + it * CHAINS;
            if (eB < E) {
                float a = P.dinv[eB];
                float val = a * (P.Snode[(size_t)P.eU[eB] * HIDC + c] +
                                 P.Snode[(size_t)P.eV[eB] * HIDC + c]) -
                            a * a * P.h[(size_t)eB * HIDC + c] + bc;
                vB[it] = val; accB += val; acc2B += val * val;
            } else vB[it] = 0.f;
        }
        devStoreF(P.partial  + cA * HIDC + c, accA);
        devStoreF(P.partial2 + cA * HIDC + c, acc2A);
        devStoreF(P.partial  + cB * HIDC + c, accB);
        devStoreF(P.partial2 + cB * HIDC + c, acc2B);
    }
    GSYNC();

    // ---- phase 2: quarter-sequential combine (bitwise == baseline kRed2),
    //      producer-consumer: waves 1-3 stream rows into an LDS ring, wave 0
    //      runs the SAME sequential 1024-add chain from LDS ----
    if (b < 8) {
        int q = b & 3;
        const float* src = ((b & 4) ? P.partial2 : P.partial) +
                           (size_t)q * (CHAINS / 4) * HIDC;
        if (t == 0) {
            sh.r.doneCnt[0] = 0; sh.r.doneCnt[1] = 0;
            sh.r.freeTok[0] = 0; sh.r.freeTok[1] = 1;
        }
        __syncthreads();
        if (w == 0) {            // consumer: lane c, channel c
            float acc = 0.f;
            for (int ch = 0; ch < 8; ch++) {
                int slot = ch & 1;
                int need = 192 * ((ch >> 1) + 1);
                while (__atomic_load_n(&sh.r.doneCnt[slot], __ATOMIC_RELAXED) < need)
                    ;
                const float* rg = &sh.r.ring[slot][0][0];
                for (int r = 0; r < 128; r++) acc += rg[r * HIDC + c];
                asm volatile("s_waitcnt lgkmcnt(0)" ::: "memory");
                __atomic_store_n(&sh.r.freeTok[slot], ch + 2, __ATOMIC_RELAXED);
            }
            devStoreF(P.miniP + b * HIDC + c, acc);
        } else {                 // producers: 192 threads
            int p = t - 64;
            for (int ch = 0; ch < 8; ch++) {
                int slot = ch & 1;
                while (__atomic_load_n(&sh.r.freeTok[slot], __ATOMIC_RELAXED) < ch)
                    ;
                const float* sbase = src + (size_t)(ch * 128) * HIDC;
                for (int idx = p; idx < 128 * 16; idx += 192) {
                    int row = idx >> 4, c4 = (idx & 15) << 2;
                    float4 v = *(const float4*)(sbase + row * HIDC + c4);
                    *(float4*)&sh.r.ring[slot][row][c4] = v;
                }
                asm volatile("s_waitcnt vmcnt(0) lgkmcnt(0)" ::: "memory");
                __atomic_fetch_add(&sh.r.doneCnt[slot], 1, __ATOMIC_RELAXED);
            }
        }
    }
    GSYNC();

    // ---- phase 3: replicated mu/var + batchnorm + relu + dot(W2) -> z ----
    {
        float Ef = (float)E;
        float mu = (((P.miniP[0 * HIDC + c] + P.miniP[1 * HIDC + c]) +
                     P.miniP[2 * HIDC + c]) + P.miniP[3 * HIDC + c]) / Ef;
        float m2 = (((P.miniP[4 * HIDC + c] + P.miniP[5 * HIDC + c]) +
                     P.miniP[6 * HIDC + c]) + P.miniP[7 * HIDC + c]) / Ef;
        float rs = rsqrtf(m2 - mu * mu + 1e-5f);
        float gc = P.gamma1[c], be = P.beta1[c], wc = P.W2[c];
#pragma unroll
        for (int it = 0; it < VMAX; it++) {
            int eA = cA + it * CHAINS;
            if (eA < E) {
                float tt = gc * (vA[it] - mu) * rs + be;
                tt = tt > 0.f ? tt : 0.f;
                float p = tt * wc;
#pragma unroll
                for (int o = 32; o > 0; o >>= 1) p += __shfl_down(p, o, 64);
                if (c == 0) devStoreF(P.z + eA, p);
            }
            int eB = cB + it * CHAINS;
            if (eB < E) {
                float tt = gc * (vB[it] - mu) * rs + be;
                tt = tt > 0.f ? tt : 0.f;
                float p = tt * wc;
#pragma unroll
                for (int o = 32; o > 0; o >>= 1) p += __shfl_down(p, o, 64);
                if (c == 0) devStoreF(P.z + eB, p);
            }
        }
    }
    GSYNC();

    // ---- phase 4: S2 per node + minOkey init ----
    if (gtid < NND) {
        int base = gtid << 6, len = P.icnt[gtid];
        float a3 = 0.f;
        for (int j = 0; j < len; j++) {
            int e = P.ilistS[base + j];
            a3 += P.z[e] * P.dinv[e];
        }
        devStoreF(P.S2 + gtid, a3);
        devStoreU64(P.minOkey + gtid, ~0ULL);
    }
    GSYNC();

    // ---- phase 5: scores + 49-bit keys + radix pass-0 histogram ----
    for (int j = t; j < SEL_BINS; j += 256) sh.m.shHist[j] = 0;
    __syncthreads();
    if (gtid < E) {
        float a = P.dinv[gtid];
        float l = a * (P.S2[P.eU[gtid]] + P.S2[P.eV[gtid]]) - a * a * P.z[gtid] +
                  P.b2[0];
        float s = 1.f / (1.f + expf(-l));
        devStoreF(P.score + gtid, s);
        u32 bb = __float_as_uint(s);
        bb = (bb >> 31) ? ~bb : (bb | 0x80000000u);
        u64 key = (((u64)bb) << 17) | (u32)(0x1FFFFu - (u32)gtid);
        devStoreU64(P.okey + gtid, key);
        atomicAdd(&sh.m.shHist[(int)((key >> 36) & (SEL_BINS - 1))], 1);
    }
    __syncthreads();
    for (int j = t; j < SEL_BINS; j += 256) {
        int vv = sh.m.shHist[j];
        if (vv) atomicAdd(&P.hist[j], vv);
    }
    GSYNC();

    // ---- phases 6..8: radix passes 1..3 with register-carried (pref,kr) ----
    int kr = E / 2;
    if (kr > NND / 2) kr = NND / 2;
    if (kr < 1) kr = 1;
    u64 pref = 1ULL << 48;
    for (int pass = 1; pass < 4; pass++) {
        selStep(P.hist + (pass - 1) * SEL_BINS, t, sh.m.aux, sh.m.shTmp,
                pref, kr, 36 - 12 * (pass - 1));
        for (int j = t; j < SEL_BINS; j += 256) sh.m.shHist[j] = 0;
        __syncthreads();
        int shift = 36 - 12 * pass;
        u64 maskHi = (~0ULL) << (shift + 12);
        if (gtid < E) {
            u64 kk = P.okey[gtid];
            if ((kk & maskHi) == pref)
                atomicAdd(&sh.m.shHist[(int)((kk >> shift) & (SEL_BINS - 1))], 1);
        }
        __syncthreads();
        int* hp = P.hist + pass * SEL_BINS;
        for (int j = t; j < SEL_BINS; j += 256) {
            int vv = sh.m.shHist[j];
            if (vv) atomicAdd(&hp[j], vv);
        }
        GSYNC();
    }

    // ---- phase 9: final digit + per-dst min over selected keys ----
    selStep(P.hist + 3 * SEL_BINS, t, sh.m.aux, sh.m.shTmp, pref, kr, 0);
    if (gtid < E) {
        u64 k = P.okey[gtid];
        if (k >= pref) atomicMin(&P.minOkey[P.eV[gtid]], k);
    }
    GSYNC();

    // ---- phase 10: cluster assignment + member scatter ----
    if (gtid < NND) {
        u64 mk = P.minOkey[gtid];
        int m = gtid;
        if (mk != ~0ULL) m = P.eU[0x1FFFFu - (u32)(mk & 0x1FFFFu)];
        devStoreI(P.n2c + gtid, m);
        devStoreI(P.present + m, 1);
        int slot = atomicAdd(&P.csize[m], 1);
        devStoreI(P.cmemb + (m << 6) + slot, gtid);
    }
    GSYNC();

    // ======== TAIL ========
    // ---- T1: scanA(present) ----
    scanAPhase(P.present, P.o2n, P.bsumsA, b, t, sh.m.shS);
    GSYNC();

    // ---- T2: pooled features + pooled-edge count + ni ----
    buildPre(P.bsumsA, sh.m.preA, t);
    for (int i = gtid; i < EUA; i += FBLK * 256) {
        int a2 = scanAt(P.o2n, sh.m.preA, P.n2c[P.ei[i]]);
        int b2 = scanAt(P.o2n, sh.m.preA, P.n2c[P.ei[EUA + i]]);
        if (a2 != b2) atomicAdd(&P.ecnt2[a2], 1);
    }
    {
        int slot = t >> 7;
        int cc = t & 127;
        for (int u = b * 2 + slot; u < NND; u += FBLK * 2) {
            if (cc == 0) devStoreI(P.ni + u, scanAt(P.o2n, sh.m.preA, P.n2c[u]));
            if (P.present[u]) {
                int s = P.csize[u];
                int base2 = u << 6;
                float acc = 0.f;
                for (int j = 0; j < s; j++)
                    acc += P.x[(size_t)P.cmemb[base2 + j] * ICH + cc];
                P.dout[(size_t)scanAt(P.o2n, sh.m.preA, u) * ICH + cc] =
                    acc / (float)s;
            }
        }
    }
    GSYNC();

    // ---- T3: scanA(ecnt2) ----
    scanAPhase(P.ecnt2, P.eoff2, P.bsumsB, b, t, sh.m.shS);
    GSYNC();

    // ---- T4: pooled-edge scatter ----
    buildPre(P.bsumsB, sh.m.preB, t);
    for (int i = gtid; i < EUA; i += FBLK * 256) {
        int a2 = P.ni[P.ei[i]], b2 = P.ni[P.ei[EUA + i]];
        if (a2 != b2) {
            int p2 = scanAt(P.eoff2, sh.m.preB, a2) + atomicAdd(&P.etmp2[a2], 1);
            devStoreI(P.bkD + p2, b2);
        }
    }
    GSYNC();

    // ---- T5: per-wave rank sort of pooled buckets ----
    for (int a2 = b * 4 + w; a2 < NND; a2 += FBLK * 4) {
        int s = scanAt(P.eoff2, sh.m.preB, a2);
        int eE = scanAt(P.eoff2, sh.m.preB, a2 + 1);
        int len = eE - s;
        for (int j = c; j < len; j += 64) {
            int vv = P.bkD[s + j];
            int r = 0;
            for (int i = 0; i < len; i++) {
                int ww = P.bkD[s + i];
                r += (ww < vv) || (ww == vv && i < j);
            }
            devStoreI(P.bkD2 + s + r, vv);
        }
        asm volatile("s_waitcnt vmcnt(0)" ::: "memory");
        int cc2 = 0;
        for (int j = c; j < len; j += 64)
            cc2 += (j == 0) || (P.bkD2[s + j] != P.bkD2[s + j - 1]);
#pragma unroll
        for (int o = 32; o > 0; o >>= 1) cc2 += __shfl_down(cc2, o, 64);
        if (c == 0) devStoreI(P.uecnt + a2, cc2);
    }
    GSYNC();

    // ---- T6: scanA(uecnt) ----
    scanAPhase(P.uecnt, P.ueoff, P.bsumsC, b, t, sh.m.shS);
    GSYNC();

    // ---- T7: pooled-edge write + batch_pool + scores + ni ----
    {
        buildPre(P.bsumsC, sh.m.preC, t);
        int M = sh.m.preA[NSCAN_B], Ep = sh.m.preC[NSCAN_B];
        size_t base3 = (size_t)M * ICH;
        int bound = (E > NND) ? E : NND;
        for (int i = gtid; i < bound; i += FBLK * 256) {
            if (i < NND) {
                int s = scanAt(P.eoff2, sh.m.preB, i);
                int e2 = scanAt(P.eoff2, sh.m.preB, i + 1);
                float* r0 = P.dout + base3;
                float* r1 = r0 + Ep;
                int o = scanAt(P.ueoff, sh.m.preC, i);
                int prev = 0;
                for (int j = s; j < e2; j++) {
                    // bkD2 lines straddle bucket boundaries -> sc1 read
                    int bj = devLoadI(P.bkD2 + j);
                    if (j == s || bj != prev) {
                        r0[o] = (float)i;
                        r1[o] = (float)bj;
                        o++;
                    }
                    prev = bj;
                }
            }
            size_t tb = base3 + 2 * (size_t)Ep;
            if (i < NND && P.present[i])
                P.dout[tb + scanAt(P.o2n, sh.m.preA, i)] = (float)P.batch[i];
            if (i < E) P.dout[tb + M + i] = P.score[i];
            if (i < NND) P.dout[tb + M + E + i] = (float)P.ni[i];
        }
    }
#undef GSYNC
}

extern "C" void kernel_launch(void* const* d_in, const int* in_sizes, int n_in,
                              void* d_out, int out_size, void* d_ws, size_t ws_size,
                              hipStream_t stream) {
    (void)in_sizes; (void)n_in; (void)ws_size; (void)out_size;
    const float* x = (const float*)d_in[0];
    const float* W1 = (const float*)d_in[1];
    const float* b1 = (const float*)d_in[2];
    const float* gamma1 = (const float*)d_in[3];
    const float* beta1 = (const float*)d_in[4];
    const float* W2 = (const float*)d_in[5];
    const float* b2 = (const float*)d_in[6];
    const int* ei = (const int*)d_in[7];
    const int* batch = (const int*)d_in[8];
    float* dout = (float*)d_out;

    char* w = (char*)d_ws;
    size_t off = 0;
    auto carve = [&](size_t bytes) -> void* {
        off = (off + 255) & ~(size_t)255;
        void* p = w + off;
        off += bytes;
        return p;
    };
    // ---- contiguous zero-init region (ONE memset) ----
    char* zero0 = w;
    int* cnt = (int*)carve(NND * 4);
    int* itmp = (int*)carve(NND * 4);
    int* icnt = (int*)carve(NND * 4);
    int* present = (int*)carve(NND * 4);
    int* csize = (int*)carve(NND * 4);
    int* ecnt2 = (int*)carve(NND * 4);
    int* etmp2 = (int*)carve(NND * 4);
    int* hist4 = (int*)carve((size_t)4 * SEL_BINS * 4);
    int* slots = (int*)carve(FBLK * 4);              // packed barrier slots
    size_t zeroBytes = off;
    // ---- rest ----
    int* ucnt = (int*)carve(NND * 4);
    int* uoff = (int*)carve((NND + 2) * 4);
    int* bsumsH = (int*)carve((NSCAN_B + 2) * 4);
    int* bsumsA = (int*)carve((NSCAN_B + 2) * 4);
    int* bsumsB = (int*)carve((NSCAN_B + 2) * 4);
    int* bsumsC = (int*)carve((NSCAN_B + 2) * 4);
    int* n2c = (int*)carve(NND * 4);
    int* o2n = (int*)carve((NND + 2) * 4);
    int* niArr = (int*)carve(NND * 4);
    int* eoff2 = (int*)carve((NND + 2) * 4);
    int* uecnt = (int*)carve(NND * 4);
    int* ueoff = (int*)carve((NND + 2) * 4);
    int* bucketV = (int*)carve((size_t)NND * BK64 * 4);
    int* bucketS = (int*)carve((size_t)NND * BK64 * 4);
    int* cmemb = (int*)carve((size_t)NND * BK64 * 4);  // own buffer: bucketV
                                                       // reuse is unsafe without
                                                       // a kernel-boundary inval
    int* eU = (int*)carve(EFE * 4);
    int* eV = (int*)carve(EFE * 4);
    int* ilist = (int*)carve((size_t)NND * BK64 * 4);
    int* ilistS = (int*)carve((size_t)NND * BK64 * 4);
    int* bkD = (int*)carve(EUA * 4);
    int* bkD2 = (int*)carve(EUA * 4);
    u64* okey = (u64*)carve(EFE * 8);
    u64* minOkey = (u64*)carve(NND * 8);
    float* dinv = (float*)carve(EFE * 4);
    float* h = (float*)carve((size_t)EFE * HIDC * 4);
    float* Snode = (float*)carve((size_t)NND * HIDC * 4);
    float* partial = (float*)carve((size_t)CHAINS * HIDC * 4);
    float* partial2 = (float*)carve((size_t)CHAINS * HIDC * 4);
    float* miniP = (float*)carve(8 * HIDC * 4);
    float* zArr = (float*)carve(EFE * 4);
    float* S2 = (float*)carve(NND * 4);
    float* score = (float*)carve(EFE * 4);

    // zero scratch (one small memset; MUST cover barrier slots pre-launch)
    hipMemsetAsync(zero0, 0, zeroBytes, stream);

    FParams fp;
    fp.ei = ei; fp.x = x; fp.W1 = W1; fp.b1 = b1; fp.gamma1 = gamma1;
    fp.beta1 = beta1; fp.W2 = W2; fp.b2 = b2; fp.batch = batch;
    fp.cnt = cnt; fp.bucketV = bucketV; fp.bucketS = bucketS; fp.ucnt = ucnt;
    fp.uoff = uoff; fp.bsumsH = bsumsH;
    fp.eU = eU; fp.eV = eV; fp.icnt = icnt; fp.itmp = itmp;
    fp.ilist = ilist; fp.ilistS = ilistS;
    fp.dinv = dinv; fp.h = h; fp.Snode = Snode;
    fp.partial = partial; fp.partial2 = partial2; fp.miniP = miniP;
    fp.z = zArr; fp.S2 = S2; fp.score = score;
    fp.okey = okey; fp.minOkey = minOkey; fp.hist = hist4;
    fp.n2c = n2c; fp.present = present; fp.csize = csize; fp.cmemb = cmemb;
    fp.o2n = o2n; fp.ni = niArr; fp.ecnt2 = ecnt2; fp.etmp2 = etmp2;
    fp.eoff2 = eoff2; fp.uecnt = uecnt; fp.ueoff = ueoff;
    fp.bkD = bkD; fp.bkD2 = bkD2;
    fp.bsumsA = bsumsA; fp.bsumsB = bsumsB; fp.bsumsC = bsumsC;
    fp.dout = dout; fp.slots = slots;
    kFusedAll<<<FBLK, 256, 0, stream>>>(fp);
}

// Round 7
// 527.738 us; speedup vs baseline: 1.2419x; 1.2419x over previous
//
#include <hip/hip_runtime.h>
#include <stdint.h>

typedef unsigned long long u64;
typedef unsigned int u32;

#define NND 20000      // nodes
#define EUA 160000     // directed input edges (2 * E_UND)
#define EFE 80000      // max clean (undirected, deduped) edges
#define ICH 128
#define HIDC 64
#define SCAN_BS 256
#define NSCAN_B ((NND + SCAN_BS - 1) / SCAN_BS)   // 79
#define PRE_N (NSCAN_B + 1)                       // 80
#define GEB 64         // edges per gemm tile
#define XS_PAD 132     // xs leading-dim pad
#define BK64 64        // fixed bucket stride (degrees Poisson(4/8), max ~25)
#define SEL_BINS 4096  // 12-bit digits, 4 passes (keys: bit48==1 always)
#define FBLK 512       // persistent grid: 2 blocks/CU on 256 CUs (all resident)
#define CHAINS 4096    // moment-reduction chains (MUST stay 4096: bitwise-
                       // identical summation order vs the verified baseline)
#define VMAX ((EFE + CHAINS - 1) / CHAINS)  // 20 edges/chain -> registers

// ---------------- agent-coherent (MALL) access helpers ----------------------
// sc1 stores complete at the Infinity Cache (cross-XCD coherence point) -> no
// wbl2/inv fences ever. Reads stay plain+cached; every communicated array is
// first plain-read only AFTER its sc1 writes completed (first-touch = fresh),
// and no buffer is re-written after having been plain-read (no stale lines).
__device__ __forceinline__ int devLoadI(const int* p) {
    return __hip_atomic_load(p, __ATOMIC_RELAXED, __HIP_MEMORY_SCOPE_AGENT);
}
__device__ __forceinline__ void devStoreI(int* p, int v) {
    __hip_atomic_store(p, v, __ATOMIC_RELAXED, __HIP_MEMORY_SCOPE_AGENT);
}
__device__ __forceinline__ void devStoreF(float* p, float v) {
    __hip_atomic_store(p, v, __ATOMIC_RELAXED, __HIP_MEMORY_SCOPE_AGENT);
}
__device__ __forceinline__ void devStoreU64(u64* p, u64 v) {
    __hip_atomic_store(p, v, __ATOMIC_RELAXED, __HIP_MEMORY_SCOPE_AGENT);
}
__device__ __forceinline__ void devStoreF4(float* p, float a0, float a1,
                                           float a2, float a3) {
    u64 w0 = ((u64)__float_as_uint(a1) << 32) | __float_as_uint(a0);
    u64 w1 = ((u64)__float_as_uint(a3) << 32) | __float_as_uint(a2);
    __hip_atomic_store((u64*)p, w0, __ATOMIC_RELAXED, __HIP_MEMORY_SCOPE_AGENT);
    __hip_atomic_store(((u64*)p) + 1, w1, __ATOMIC_RELAXED, __HIP_MEMORY_SCOPE_AGENT);
}

// ---------------- grid barrier v3: two-level arrival + single-line poll -----
// Round-5 lesson: 512x256 threads sweeping 16 slot lines = MALL read-queue
// collapse (~15us/barrier). v3 minimizes MALL ops: arrival = 1 RMW/block over
// 8 padded sub-lines (64-deep chains, pipelined with arrival skew); last
// arriver of each group RMWs gdone (8 ops); 8th group publishes ep; ONLY
// thread 0 of each block polls ep with ~0.3us s_sleep backoff. Monotonic
// counters, no reset/ABA. Ordering: each block's vmcnt(0)-drained sc1 stores
// precede its arrival RMW; waiters observe ep only after the last arrival ->
// all data at MALL; first-touch plain reads then fetch fresh lines.
__device__ __forceinline__ void gsync(int* sub, int* gdone, int* ep,
                                      int b, int ph) {
    asm volatile("s_waitcnt vmcnt(0)" ::: "memory");
    __syncthreads();
    if (threadIdx.x == 0) {
        int old = atomicAdd(&sub[(b & 7) << 4], 1);         // device-scope RMW
        if (old == ph * 64 + 63) {                          // last of my group
            int g = atomicAdd(gdone, 1);
            if (g == ph * 8 + 7) devStoreI(ep, ph + 1);     // 8th group: publish
        }
        while (devLoadI(ep) < ph + 1) __builtin_amdgcn_s_sleep(12);
    }
    __syncthreads();
    asm volatile("" ::: "memory");
}

// ---------------- LDS union (max member = GEMM 66.5 KB) ---------------------
union ShU {
    struct { float W1s[ICH][HIDC]; float xs[GEB][XS_PAD]; } g;        // 66.5KB
    struct { int shHist[SEL_BINS]; int aux[256]; int shTmp[2];
             int shS[SCAN_BS]; int preA[PRE_N]; int preB[PRE_N];
             int preC[PRE_N]; } m;                                    // ~19KB
    struct { float ring[2][128][HIDC]; int doneCnt[2]; int freeTok[2]; } r; // 64KB
};

struct FParams {
    // inputs
    const int* ei; const float* x; const float* W1; const float* b1;
    const float* gamma1; const float* beta1; const float* W2; const float* b2;
    const int* batch;
    // scratch
    int* cnt; int* bucketV; int* bucketS; int* ucnt; int* uoff; int* bsumsH;
    int* eU; int* eV; int* icnt; int* itmp; int* ilist; int* ilistS;
    float* dinv; float* h; float* Snode; float* partial; float* partial2;
    float* miniP; float* z; float* S2; float* score;
    u64* okey; u64* minOkey; int* hist;
    int* n2c; int* present; int* csize; int* cmemb;
    int* o2n; int* ni; int* ecnt2; int* etmp2; int* eoff2;
    int* uecnt; int* ueoff; int* bkD; int* bkD2;
    int* bsumsA; int* bsumsB; int* bsumsC;
    float* dout;
    int* sub; int* gdone; int* ep;
};

// in-kernel exclusive scan, phase A (blocks 0..78); consumers rebuild the
// 79-entry block prefix in LDS (integer-exact == baseline scanA+scanB).
__device__ __forceinline__ void scanAPhase(const int* in, int* rawOut, int* bsums,
                                           int b, int t, int* shS) {
    if (b >= NSCAN_B) return;            // block-uniform branch
    int i = b * SCAN_BS + t;
    int v = (i < NND) ? in[i] : 0;
    shS[t] = v;
    __syncthreads();
    for (int o = 1; o < SCAN_BS; o <<= 1) {
        int tv = (t >= o) ? shS[t - o] : 0;
        __syncthreads();
        shS[t] += tv;
        __syncthreads();
    }
    if (i <= NND) devStoreI(rawOut + i, shS[t] - v);
    if (t == SCAN_BS - 1) devStoreI(bsums + b, shS[t]);
}
__device__ __forceinline__ void buildPre(const int* bsums, int* pre, int t) {
    if (t < NSCAN_B) pre[t + 1] = bsums[t];
    if (t == 0) pre[0] = 0;
    __syncthreads();
    if (t == 0)
        for (int k = 1; k <= NSCAN_B; k++) pre[k] += pre[k - 1];
    __syncthreads();
}
__device__ __forceinline__ int scanAt(const int* raw, const int* pre, int i) {
    return raw[i] + pre[i >> 8];         // valid for 0 <= i <= NND
}

// one radix-select q-step (12 bits); carried (pref, kr) across phases makes
// the baseline's full replay unnecessary -- integer-identical results.
__device__ __forceinline__ void selStep(const int* hq, int t, int* aux, int* shTmp,
                                        u64& pref, int& kr, int shift) {
    int b16[16]; int g = 0;
#pragma unroll
    for (int j = 0; j < 16; j++) { b16[j] = hq[16 * t + j]; g += b16[j]; }
    aux[t] = g;
    __syncthreads();
    for (int o = 1; o < 256; o <<= 1) {
        int v = (t + o < 256) ? aux[t + o] : 0;
        __syncthreads();
        aux[t] += v;
        __syncthreads();
    }
    int suf = aux[t] - g;
    if (suf < kr && kr <= suf + g) {
        int cum = suf, found = 16 * t;
        for (int j = 15; j >= 0; j--) {
            int hc = b16[j];
            if (cum + hc >= kr) { found = 16 * t + j; break; }
            cum += hc;
        }
        shTmp[0] = found;
        shTmp[1] = kr - cum;
    }
    __syncthreads();
    pref |= ((u64)shTmp[0]) << shift;
    kr = shTmp[1];
    __syncthreads();
}

// wave-parallel rank sort over stride-64 buckets (grid-stride, 4 waves/block)
__device__ __forceinline__ void rs64Phase(const int* in, int* out,
                                          const int* lenA, int* ucnt,
                                          int b, int w, int c) {
    for (int a = b * 4 + w; a < NND; a += FBLK * 4) {
        int len = lenA[a];
        int base = a << 6;
        for (int j = c; j < len; j += 64) {
            int v = in[base + j];
            int r = 0;
            for (int i = 0; i < len; i++) {
                int wv = in[base + i];
                r += (wv < v) || (wv == v && i < j);
            }
            devStoreI(out + base + r, v);
        }
        asm volatile("s_waitcnt vmcnt(0)" ::: "memory");
        int cc = 0;
        for (int j = c; j < len; j += 64)
            cc += (j == 0) || (out[base + j] != out[base + j - 1]);
#pragma unroll
        for (int o = 32; o > 0; o >>= 1) cc += __shfl_down(cc, o, 64);
        if (c == 0) devStoreI(ucnt + a, cc);
    }
}

__global__ __launch_bounds__(256, 2) void kFusedAll(FParams P) {
    __shared__ ShU sh;
    int t = threadIdx.x;
    int b = blockIdx.x;
    int gtid = b * 256 + t;
    int w = t >> 6, c = t & 63;
    int ph = 0;
    int E = 0;
#define GSYNC() do { gsync(P.sub, P.gdone, P.ep, b, ph); ph++; } while (0)

    // ======== HEAD ========
    // ---- C1: filter (s<d) -> stride-64 buckets ----
    for (int i = gtid; i < EUA; i += FBLK * 256) {
        int s = P.ei[i], d = P.ei[EUA + i];
        if (s < d) {
            int p = atomicAdd(&P.cnt[s], 1);
            devStoreI(P.bucketV + (s << 6) + p, d);
        }
    }
    GSYNC();

    // ---- C2: rank-sort buckets + unique count ----
    rs64Phase(P.bucketV, P.bucketS, P.cnt, P.ucnt, b, w, c);
    GSYNC();

    // ---- C3: scanA(ucnt) -> uoffRaw, bsumsH ----
    scanAPhase(P.ucnt, P.uoff, P.bsumsH, b, t, sh.m.shS);
    GSYNC();

    // ---- C4: compact + incidence count; E becomes register-carried ----
    buildPre(P.bsumsH, sh.m.preA, t);
    E = sh.m.preA[NSCAN_B];
    if (gtid < NND) {
        int u = gtid;
        int s = u << 6, e = s + P.cnt[u];
        int o = scanAt(P.uoff, sh.m.preA, u);
        int myc = 0;
        for (int i = s; i < e; i++)
            if (i == s || P.bucketS[i] != P.bucketS[i - 1]) {
                devStoreI(P.eU + o, u);
                devStoreI(P.eV + o, P.bucketS[i]);
                o++;
                atomicAdd(&P.icnt[P.bucketS[i]], 1);
                myc++;
            }
        if (myc) atomicAdd(&P.icnt[u], myc);
    }
    GSYNC();

    // ---- C5: incidence scatter + dinv ----
    if (gtid < E) {
        int u = P.eU[gtid], v = P.eV[gtid];
        devStoreI(P.ilist + (u << 6) + atomicAdd(&P.itmp[u], 1), gtid);
        devStoreI(P.ilist + (v << 6) + atomicAdd(&P.itmp[v], 1), gtid);
        devStoreF(P.dinv + gtid, rsqrtf((float)(P.icnt[u] + P.icnt[v] - 1)));
    }
    GSYNC();

    // ---- C6: GEMM h = (0.5*(x[u]+x[v])) @ W1  +  rank-sort(ilist) ----
    {
        const float4* Wv = (const float4*)P.W1;
        float4* Ws = (float4*)&sh.g.W1s[0][0];
        for (int i = t; i < ICH * HIDC / 4; i += 256) Ws[i] = Wv[i];
        int nTiles = (E + GEB - 1) / GEB;
        for (int tile = b; tile < nTiles; tile += FBLK) {
            int e0 = tile * GEB;
            __syncthreads();
            {
                int eb = t >> 2, q = t & 3;
                int e = e0 + eb;
                if (e < E) {
                    int u = P.eU[e], v = P.eV[e];
                    const float4* xu = (const float4*)(P.x + (size_t)u * ICH) + q * 8;
                    const float4* xv = (const float4*)(P.x + (size_t)v * ICH) + q * 8;
                    float* xd = &sh.g.xs[eb][q * 32];
#pragma unroll
                    for (int i = 0; i < 8; i++) {
                        float4 a = xu[i], bb = xv[i];
                        xd[i * 4 + 0] = 0.5f * (a.x + bb.x);
                        xd[i * 4 + 1] = 0.5f * (a.y + bb.y);
                        xd[i * 4 + 2] = 0.5f * (a.z + bb.z);
                        xd[i * 4 + 3] = 0.5f * (a.w + bb.w);
                    }
                }
            }
            __syncthreads();
            int cg4 = (t & 15) * 4;
            int es = t >> 4;
            float a00=0,a01=0,a02=0,a03=0, a10=0,a11=0,a12=0,a13=0;
            float a20=0,a21=0,a22=0,a23=0, a30=0,a31=0,a32=0,a33=0;
#pragma unroll 4
            for (int k = 0; k < ICH; k++) {
                float4 wv = *(const float4*)&sh.g.W1s[k][cg4];
                float x0 = sh.g.xs[es][k],      x1 = sh.g.xs[es + 16][k];
                float x2 = sh.g.xs[es + 32][k], x3 = sh.g.xs[es + 48][k];
                a00 += x0*wv.x; a01 += x0*wv.y; a02 += x0*wv.z; a03 += x0*wv.w;
                a10 += x1*wv.x; a11 += x1*wv.y; a12 += x1*wv.z; a13 += x1*wv.w;
                a20 += x2*wv.x; a21 += x2*wv.y; a22 += x2*wv.z; a23 += x2*wv.w;
                a30 += x3*wv.x; a31 += x3*wv.y; a32 += x3*wv.z; a33 += x3*wv.w;
            }
            int e;
            e = e0 + es;      if (e < E) devStoreF4(&P.h[(size_t)e*HIDC + cg4], a00,a01,a02,a03);
            e = e0 + es + 16; if (e < E) devStoreF4(&P.h[(size_t)e*HIDC + cg4], a10,a11,a12,a13);
            e = e0 + es + 32; if (e < E) devStoreF4(&P.h[(size_t)e*HIDC + cg4], a20,a21,a22,a23);
            e = e0 + es + 48; if (e < E) devStoreF4(&P.h[(size_t)e*HIDC + cg4], a30,a31,a32,a33);
        }
    }
    rs64Phase(P.ilist, P.ilistS, P.icnt, P.ucnt, b, w, c);  // ucnt = dummy
    GSYNC();

    // ======== MID-CHAIN ========
    // ---- phase 0: Snode[n][c] (== kSGather) ----
    for (int id = gtid; id < NND * HIDC; id += FBLK * 256) {
        int n = id >> 6;
        int base = n << 6, len = P.icnt[n];
        float acc = 0.f;
        for (int j = 0; j < len; j++) {
            int ed = P.ilistS[base + j];
            acc += P.h[(size_t)ed * HIDC + c] * P.dinv[ed];
        }
        devStoreF(P.Snode + id, acc);
    }
    GSYNC();

    // ---- phase 1: conv1 epilogue in regs + per-chain moments ----
    int gw = b * 4 + w;
    int cA = 2 * gw, cB = cA + 1;
    float vA[VMAX], vB[VMAX];
    {
        float bc = P.b1[c];
        float accA = 0.f, acc2A = 0.f, accB = 0.f, acc2B = 0.f;
#pragma unroll
        for (int it = 0; it < VMAX; it++) {
            int eA = cA + it * CHAINS;
            if (eA < E) {
                float a = P.dinv[eA];
                float val = a * (P.Snode[(size_t)P.eU[eA] * HIDC + c] +
                                 P.Snode[(size_t)P.eV[eA] * HIDC + c]) -
                            a * a * P.h[(size_t)eA * HIDC + c] + bc;
                vA[it] = val; accA += val; acc2A += val * val;
            } else vA[it] = 0.f;
            int eB = cB + it * CHAINS;
            if (eB < E) {
                float a = P.dinv[eB];
                float val = a * (P.Snode[(size_t)P.eU[eB] * HIDC + c] +
                                 P.Snode[(size_t)P.eV[eB] * HIDC + c]) -
                            a * a * P.h[(size_t)eB * HIDC + c] + bc;
                vB[it] = val; accB += val; acc2B += val * val;
            } else vB[it] = 0.f;
        }
        devStoreF(P.partial  + cA * HIDC + c, accA);
        devStoreF(P.partial2 + cA * HIDC + c, acc2A);
        devStoreF(P.partial  + cB * HIDC + c, accB);
        devStoreF(P.partial2 + cB * HIDC + c, acc2B);
    }
    GSYNC();

    // ---- phase 2: quarter-sequential combine (bitwise == baseline kRed2),
    //      producer-consumer: waves 1-3 stream rows into an LDS ring, wave 0
    //      runs the SAME sequential 1024-add chain from LDS ----
    if (b < 8) {
        int q = b & 3;
        const float* src = ((b & 4) ? P.partial2 : P.partial) +
                           (size_t)q * (CHAINS / 4) * HIDC;
        if (t == 0) {
            sh.r.doneCnt[0] = 0; sh.r.doneCnt[1] = 0;
            sh.r.freeTok[0] = 0; sh.r.freeTok[1] = 1;
        }
        __syncthreads();
        if (w == 0) {            // consumer: lane c, channel c
            float acc = 0.f;
            for (int ch = 0; ch < 8; ch++) {
                int slot = ch & 1;
                int need = 192 * ((ch >> 1) + 1);
                while (__atomic_load_n(&sh.r.doneCnt[slot], __ATOMIC_RELAXED) < need)
                    ;
                const float* rg = &sh.r.ring[slot][0][0];
                for (int r = 0; r < 128; r++) acc += rg[r * HIDC + c];
                asm volatile("s_waitcnt lgkmcnt(0)" ::: "memory");
                __atomic_store_n(&sh.r.freeTok[slot], ch + 2, __ATOMIC_RELAXED);
            }
            devStoreF(P.miniP + b * HIDC + c, acc);
        } else {                 // producers: 192 threads
            int p = t - 64;
            for (int ch = 0; ch < 8; ch++) {
                int slot = ch & 1;
                while (__atomic_load_n(&sh.r.freeTok[slot], __ATOMIC_RELAXED) < ch)
                    ;
                const float* sbase = src + (size_t)(ch * 128) * HIDC;
                for (int idx = p; idx < 128 * 16; idx += 192) {
                    int row = idx >> 4, c4 = (idx & 15) << 2;
                    float4 v = *(const float4*)(sbase + row * HIDC + c4);
                    *(float4*)&sh.r.ring[slot][row][c4] = v;
                }
                asm volatile("s_waitcnt vmcnt(0) lgkmcnt(0)" ::: "memory");
                __atomic_fetch_add(&sh.r.doneCnt[slot], 1, __ATOMIC_RELAXED);
            }
        }
    }
    GSYNC();

    // ---- phase 3: replicated mu/var + batchnorm + relu + dot(W2) -> z ----
    {
        float Ef = (float)E;
        float mu = (((P.miniP[0 * HIDC + c] + P.miniP[1 * HIDC + c]) +
                     P.miniP[2 * HIDC + c]) + P.miniP[3 * HIDC + c]) / Ef;
        float m2 = (((P.miniP[4 * HIDC + c] + P.miniP[5 * HIDC + c]) +
                     P.miniP[6 * HIDC + c]) + P.miniP[7 * HIDC + c]) / Ef;
        float rs = rsqrtf(m2 - mu * mu + 1e-5f);
        float gc = P.gamma1[c], be = P.beta1[c], wc = P.W2[c];
#pragma unroll
        for (int it = 0; it < VMAX; it++) {
            int eA = cA + it * CHAINS;
            if (eA < E) {
                float tt = gc * (vA[it] - mu) * rs + be;
                tt = tt > 0.f ? tt : 0.f;
                float p = tt * wc;
#pragma unroll
                for (int o = 32; o > 0; o >>= 1) p += __shfl_down(p, o, 64);
                if (c == 0) devStoreF(P.z + eA, p);
            }
            int eB = cB + it * CHAINS;
            if (eB < E) {
                float tt = gc * (vB[it] - mu) * rs + be;
                tt = tt > 0.f ? tt : 0.f;
                float p = tt * wc;
#pragma unroll
                for (int o = 32; o > 0; o >>= 1) p += __shfl_down(p, o, 64);
                if (c == 0) devStoreF(P.z + eB, p);
            }
        }
    }
    GSYNC();

    // ---- phase 4: S2 per node + minOkey init ----
    if (gtid < NND) {
        int base = gtid << 6, len = P.icnt[gtid];
        float a3 = 0.f;
        for (int j = 0; j < len; j++) {
            int e = P.ilistS[base + j];
            a3 += P.z[e] * P.dinv[e];
        }
        devStoreF(P.S2 + gtid, a3);
        devStoreU64(P.minOkey + gtid, ~0ULL);
    }
    GSYNC();

    // ---- phase 5: scores + 49-bit keys + radix pass-0 histogram ----
    for (int j = t; j < SEL_BINS; j += 256) sh.m.shHist[j] = 0;
    __syncthreads();
    if (gtid < E) {
        float a = P.dinv[gtid];
        float l = a * (P.S2[P.eU[gtid]] + P.S2[P.eV[gtid]]) - a * a * P.z[gtid] +
                  P.b2[0];
        float s = 1.f / (1.f + expf(-l));
        devStoreF(P.score + gtid, s);
        u32 bb = __float_as_uint(s);
        bb = (bb >> 31) ? ~bb : (bb | 0x80000000u);
        u64 key = (((u64)bb) << 17) | (u32)(0x1FFFFu - (u32)gtid);
        devStoreU64(P.okey + gtid, key);
        atomicAdd(&sh.m.shHist[(int)((key >> 36) & (SEL_BINS - 1))], 1);
    }
    __syncthreads();
    for (int j = t; j < SEL_BINS; j += 256) {
        int vv = sh.m.shHist[j];
        if (vv) atomicAdd(&P.hist[j], vv);
    }
    GSYNC();

    // ---- phases 6..8: radix passes 1..3 with register-carried (pref,kr) ----
    int kr = E / 2;
    if (kr > NND / 2) kr = NND / 2;
    if (kr < 1) kr = 1;
    u64 pref = 1ULL << 48;
    for (int pass = 1; pass < 4; pass++) {
        selStep(P.hist + (pass - 1) * SEL_BINS, t, sh.m.aux, sh.m.shTmp,
                pref, kr, 36 - 12 * (pass - 1));
        for (int j = t; j < SEL_BINS; j += 256) sh.m.shHist[j] = 0;
        __syncthreads();
        int shift = 36 - 12 * pass;
        u64 maskHi = (~0ULL) << (shift + 12);
        if (gtid < E) {
            u64 kk = P.okey[gtid];
            if ((kk & maskHi) == pref)
                atomicAdd(&sh.m.shHist[(int)((kk >> shift) & (SEL_BINS - 1))], 1);
        }
        __syncthreads();
        int* hp = P.hist + pass * SEL_BINS;
        for (int j = t; j < SEL_BINS; j += 256) {
            int vv = sh.m.shHist[j];
            if (vv) atomicAdd(&hp[j], vv);
        }
        GSYNC();
    }

    // ---- phase 9: final digit + per-dst min over selected keys ----
    selStep(P.hist + 3 * SEL_BINS, t, sh.m.aux, sh.m.shTmp, pref, kr, 0);
    if (gtid < E) {
        u64 k = P.okey[gtid];
        if (k >= pref) atomicMin(&P.minOkey[P.eV[gtid]], k);
    }
    GSYNC();

    // ---- phase 10: cluster assignment + member scatter ----
    if (gtid < NND) {
        u64 mk = P.minOkey[gtid];
        int m = gtid;
        if (mk != ~0ULL) m = P.eU[0x1FFFFu - (u32)(mk & 0x1FFFFu)];
        devStoreI(P.n2c + gtid, m);
        devStoreI(P.present + m, 1);
        int slot = atomicAdd(&P.csize[m], 1);
        devStoreI(P.cmemb + (m << 6) + slot, gtid);
    }
    GSYNC();

    // ======== TAIL ========
    // ---- T1: scanA(present) ----
    scanAPhase(P.present, P.o2n, P.bsumsA, b, t, sh.m.shS);
    GSYNC();

    // ---- T2: pooled features + pooled-edge count + ni ----
    buildPre(P.bsumsA, sh.m.preA, t);
    for (int i = gtid; i < EUA; i += FBLK * 256) {
        int a2 = scanAt(P.o2n, sh.m.preA, P.n2c[P.ei[i]]);
        int b2 = scanAt(P.o2n, sh.m.preA, P.n2c[P.ei[EUA + i]]);
        if (a2 != b2) atomicAdd(&P.ecnt2[a2], 1);
    }
    {
        int slot = t >> 7;
        int cc = t & 127;
        for (int u = b * 2 + slot; u < NND; u += FBLK * 2) {
            if (cc == 0) devStoreI(P.ni + u, scanAt(P.o2n, sh.m.preA, P.n2c[u]));
            if (P.present[u]) {
                int s = P.csize[u];
                int base2 = u << 6;
                float acc = 0.f;
                for (int j = 0; j < s; j++)
                    acc += P.x[(size_t)P.cmemb[base2 + j] * ICH + cc];
                P.dout[(size_t)scanAt(P.o2n, sh.m.preA, u) * ICH + cc] =
                    acc / (float)s;
            }
        }
    }
    GSYNC();

    // ---- T3: scanA(ecnt2) ----
    scanAPhase(P.ecnt2, P.eoff2, P.bsumsB, b, t, sh.m.shS);
    GSYNC();

    // ---- T4: pooled-edge scatter ----
    buildPre(P.bsumsB, sh.m.preB, t);
    for (int i = gtid; i < EUA; i += FBLK * 256) {
        int a2 = P.ni[P.ei[i]], b2 = P.ni[P.ei[EUA + i]];
        if (a2 != b2) {
            int p2 = scanAt(P.eoff2, sh.m.preB, a2) + atomicAdd(&P.etmp2[a2], 1);
            devStoreI(P.bkD + p2, b2);
        }
    }
    GSYNC();

    // ---- T5: per-wave rank sort of pooled buckets ----
    for (int a2 = b * 4 + w; a2 < NND; a2 += FBLK * 4) {
        int s = scanAt(P.eoff2, sh.m.preB, a2);
        int eE = scanAt(P.eoff2, sh.m.preB, a2 + 1);
        int len = eE - s;
        for (int j = c; j < len; j += 64) {
            int vv = P.bkD[s + j];
            int r = 0;
            for (int i = 0; i < len; i++) {
                int ww = P.bkD[s + i];
                r += (ww < vv) || (ww == vv && i < j);
            }
            devStoreI(P.bkD2 + s + r, vv);
        }
        asm volatile("s_waitcnt vmcnt(0)" ::: "memory");
        int cc2 = 0;
        for (int j = c; j < len; j += 64)
            cc2 += (j == 0) || (P.bkD2[s + j] != P.bkD2[s + j - 1]);
#pragma unroll
        for (int o = 32; o > 0; o >>= 1) cc2 += __shfl_down(cc2, o, 64);
        if (c == 0) devStoreI(P.uecnt + a2, cc2);
    }
    GSYNC();

    // ---- T6: scanA(uecnt) ----
    scanAPhase(P.uecnt, P.ueoff, P.bsumsC, b, t, sh.m.shS);
    GSYNC();

    // ---- T7: pooled-edge write + batch_pool + scores + ni ----
    {
        buildPre(P.bsumsC, sh.m.preC, t);
        int M = sh.m.preA[NSCAN_B], Ep = sh.m.preC[NSCAN_B];
        size_t base3 = (size_t)M * ICH;
        int bound = (E > NND) ? E : NND;
        for (int i = gtid; i < bound; i += FBLK * 256) {
            if (i < NND) {
                int s = scanAt(P.eoff2, sh.m.preB, i);
                int e2 = scanAt(P.eoff2, sh.m.preB, i + 1);
                float* r0 = P.dout + base3;
                float* r1 = r0 + Ep;
                int o = scanAt(P.ueoff, sh.m.preC, i);
                int prev = 0;
                for (int j = s; j < e2; j++) {
                    // bkD2 lines straddle bucket boundaries -> sc1 read
                    int bj = devLoadI(P.bkD2 + j);
                    if (j == s || bj != prev) {
                        r0[o] = (float)i;
                        r1[o] = (float)bj;
                        o++;
                    }
                    prev = bj;
                }
            }
            size_t tb = base3 + 2 * (size_t)Ep;
            if (i < NND && P.present[i])
                P.dout[tb + scanAt(P.o2n, sh.m.preA, i)] = (float)P.batch[i];
            if (i < E) P.dout[tb + M + i] = P.score[i];
            if (i < NND) P.dout[tb + M + E + i] = (float)P.ni[i];
        }
    }
#undef GSYNC
}

extern "C" void kernel_launch(void* const* d_in, const int* in_sizes, int n_in,
                              void* d_out, int out_size, void* d_ws, size_t ws_size,
                              hipStream_t stream) {
    (void)in_sizes; (void)n_in; (void)ws_size; (void)out_size;
    const float* x = (const float*)d_in[0];
    const float* W1 = (const float*)d_in[1];
    const float* b1 = (const float*)d_in[2];
    const float* gamma1 = (const float*)d_in[3];
    const float* beta1 = (const float*)d_in[4];
    const float* W2 = (const float*)d_in[5];
    const float* b2 = (const float*)d_in[6];
    const int* ei = (const int*)d_in[7];
    const int* batch = (const int*)d_in[8];
    float* dout = (float*)d_out;

    char* w = (char*)d_ws;
    size_t off = 0;
    auto carve = [&](size_t bytes) -> void* {
        off = (off + 255) & ~(size_t)255;
        void* p = w + off;
        off += bytes;
        return p;
    };
    // ---- contiguous zero-init region (ONE memset) ----
    char* zero0 = w;
    int* cnt = (int*)carve(NND * 4);
    int* itmp = (int*)carve(NND * 4);
    int* icnt = (int*)carve(NND * 4);
    int* present = (int*)carve(NND * 4);
    int* csize = (int*)carve(NND * 4);
    int* ecnt2 = (int*)carve(NND * 4);
    int* etmp2 = (int*)carve(NND * 4);
    int* hist4 = (int*)carve((size_t)4 * SEL_BINS * 4);
    int* sub = (int*)carve(8 * 16 * 4);              // arrival sub-counters
    int* gdone = (int*)carve(16 * 4);                // group-done counter
    int* ep = (int*)carve(16 * 4);                   // published epoch
    size_t zeroBytes = off;
    // ---- rest ----
    int* ucnt = (int*)carve(NND * 4);
    int* uoff = (int*)carve((NND + 2) * 4);
    int* bsumsH = (int*)carve((NSCAN_B + 2) * 4);
    int* bsumsA = (int*)carve((NSCAN_B + 2) * 4);
    int* bsumsB = (int*)carve((NSCAN_B + 2) * 4);
    int* bsumsC = (int*)carve((NSCAN_B + 2) * 4);
    int* n2c = (int*)carve(NND * 4);
    int* o2n = (int*)carve((NND + 2) * 4);
    int* niArr = (int*)carve(NND * 4);
    int* eoff2 = (int*)carve((NND + 2) * 4);
    int* uecnt = (int*)carve(NND * 4);
    int* ueoff = (int*)carve((NND + 2) * 4);
    int* bucketV = (int*)carve((size_t)NND * BK64 * 4);
    int* bucketS = (int*)carve((size_t)NND * BK64 * 4);
    int* cmemb = (int*)carve((size_t)NND * BK64 * 4);
    int* eU = (int*)carve(EFE * 4);
    int* eV = (int*)carve(EFE * 4);
    int* ilist = (int*)carve((size_t)NND * BK64 * 4);
    int* ilistS = (int*)carve((size_t)NND * BK64 * 4);
    int* bkD = (int*)carve(EUA * 4);
    int* bkD2 = (int*)carve(EUA * 4);
    u64* okey = (u64*)carve(EFE * 8);
    u64* minOkey = (u64*)carve(NND * 8);
    float* dinv = (float*)carve(EFE * 4);
    float* h = (float*)carve((size_t)EFE * HIDC * 4);
    float* Snode = (float*)carve((size_t)NND * HIDC * 4);
    float* partial = (float*)carve((size_t)CHAINS * HIDC * 4);
    float* partial2 = (float*)carve((size_t)CHAINS * HIDC * 4);
    float* miniP = (float*)carve(8 * HIDC * 4);
    float* zArr = (float*)carve(EFE * 4);
    float* S2 = (float*)carve(NND * 4);
    float* score = (float*)carve(EFE * 4);

    // zero scratch (one small memset; MUST cover barrier counters pre-launch)
    hipMemsetAsync(zero0, 0, zeroBytes, stream);

    FParams fp;
    fp.ei = ei; fp.x = x; fp.W1 = W1; fp.b1 = b1; fp.gamma1 = gamma1;
    fp.beta1 = beta1; fp.W2 = W2; fp.b2 = b2; fp.batch = batch;
    fp.cnt = cnt; fp.bucketV = bucketV; fp.bucketS = bucketS; fp.ucnt = ucnt;
    fp.uoff = uoff; fp.bsumsH = bsumsH;
    fp.eU = eU; fp.eV = eV; fp.icnt = icnt; fp.itmp = itmp;
    fp.ilist = ilist; fp.ilistS = ilistS;
    fp.dinv = dinv; fp.h = h; fp.Snode = Snode;
    fp.partial = partial; fp.partial2 = partial2; fp.miniP = miniP;
    fp.z = zArr; fp.S2 = S2; fp.score = score;
    fp.okey = okey; fp.minOkey = minOkey; fp.hist = hist4;
    fp.n2c = n2c; fp.present = present; fp.csize = csize; fp.cmemb = cmemb;
    fp.o2n = o2n; fp.ni = niArr; fp.ecnt2 = ecnt2; fp.etmp2 = etmp2;
    fp.eoff2 = eoff2; fp.uecnt = uecnt; fp.ueoff = ueoff;
    fp.bkD = bkD; fp.bkD2 = bkD2;
    fp.bsumsA = bsumsA; fp.bsumsB = bsumsB; fp.bsumsC = bsumsC;
    fp.dout = dout;
    fp.sub = sub; fp.gdone = gdone; fp.ep = ep;
    kFusedAll<<<FBLK, 256, 0, stream>>>(fp);
}

// Round 8
// 503.631 us; speedup vs baseline: 1.3013x; 1.0479x over previous
//
#include <hip/hip_runtime.h>
#include <stdint.h>

typedef unsigned long long u64;
typedef unsigned int u32;

#define NND 20000      // nodes
#define EUA 160000     // directed input edges (2 * E_UND)
#define EFE 80000      // max clean (undirected, deduped) edges
#define ICH 128
#define HIDC 64
#define SCAN_BS 256
#define NSCAN_B ((NND + SCAN_BS - 1) / SCAN_BS)   // 79
#define PRE_N (NSCAN_B + 1)                       // 80
#define GEB 32         // edges per gemm tile (32 -> union 48.5KB -> 3 blk/CU)
#define XS_PAD 132     // xs leading-dim pad
#define BK64 64        // fixed bucket stride (degrees Poisson(4/8), max ~25)
#define SEL_BINS 4096  // 12-bit digits, 4 passes (keys: bit48==1 always)
#define FBLK 768       // persistent grid: 3 blocks/CU on 256 CUs (all resident)
#define NGRP 64        // barrier arrival sub-lines
#define GRPSZ (FBLK / NGRP)                 // 12 arrivals per sub-line
#define CHAINS 4096    // moment-reduction chains (MUST stay 4096: bitwise-
                       // identical summation order vs the verified baseline)
#define VMAX ((EFE + CHAINS - 1) / CHAINS)  // 20 edges/chain -> registers

// ---------------- agent-coherent (MALL) access helpers ----------------------
// sc1 stores complete at the Infinity Cache (cross-XCD coherence point) -> no
// wbl2/inv fences ever. Reads stay plain+cached; every communicated array is
// first plain-read only AFTER its sc1 writes completed (first-touch = fresh).
__device__ __forceinline__ int devLoadI(const int* p) {
    return __hip_atomic_load(p, __ATOMIC_RELAXED, __HIP_MEMORY_SCOPE_AGENT);
}
__device__ __forceinline__ void devStoreI(int* p, int v) {
    __hip_atomic_store(p, v, __ATOMIC_RELAXED, __HIP_MEMORY_SCOPE_AGENT);
}
__device__ __forceinline__ void devStoreF(float* p, float v) {
    __hip_atomic_store(p, v, __ATOMIC_RELAXED, __HIP_MEMORY_SCOPE_AGENT);
}
__device__ __forceinline__ void devStoreU64(u64* p, u64 v) {
    __hip_atomic_store(p, v, __ATOMIC_RELAXED, __HIP_MEMORY_SCOPE_AGENT);
}
__device__ __forceinline__ void devStoreF4(float* p, float a0, float a1,
                                           float a2, float a3) {
    u64 w0 = ((u64)__float_as_uint(a1) << 32) | __float_as_uint(a0);
    u64 w1 = ((u64)__float_as_uint(a3) << 32) | __float_as_uint(a2);
    __hip_atomic_store((u64*)p, w0, __ATOMIC_RELAXED, __HIP_MEMORY_SCOPE_AGENT);
    __hip_atomic_store(((u64*)p) + 1, w1, __ATOMIC_RELAXED, __HIP_MEMORY_SCOPE_AGENT);
}

// ---------------- grid barrier v4: RMW tree + relay fan-out -----------------
// Round-7 lesson: one 64-deep same-line RMW chain = ~7us. v4: arrival spread
// over 64 padded sub-lines (chain 12, pipelined with skew) -> last-of-group
// bumps one of 8 mid-lines (chain 8) -> last bumps fin (chain 8) -> publish
// ep. Polling: 8 leader blocks poll ep, store to 8 relay lines; others poll
// their relay line (~95 pollers/line, 768-cyc sleep) -- no MALL queue
// collapse (round-5 lesson). Monotonic counters, no reset/ABA. Ordering:
// vmcnt(0)-drained sc1 stores precede arrival; waiters observe only after
// the last arrival -> all data at MALL; first-touch plain reads are fresh.
__device__ __forceinline__ void gsync(int* sub, int* mid, int* fin, int* ep,
                                      int* relay, int b, int ph) {
    asm volatile("s_waitcnt vmcnt(0)" ::: "memory");
    __syncthreads();
    if (threadIdx.x == 0) {
        int s = b & (NGRP - 1);
        int old = atomicAdd(&sub[s << 4], 1);
        if (old == ph * GRPSZ + (GRPSZ - 1)) {      // last of my 12-group
            int om = atomicAdd(&mid[(s & 7) << 4], 1);
            if (om == ph * 8 + 7) {                 // last of my mid-group
                int of = atomicAdd(fin, 1);
                if (of == ph * 8 + 7) devStoreI(ep, ph + 1);
            }
        }
        if (b < 8) {                                // relay leaders
            while (devLoadI(ep) < ph + 1) __builtin_amdgcn_s_sleep(4);
            devStoreI(&relay[b << 4], ph + 1);
        } else {
            const int* rl = &relay[(b & 7) << 4];
            while (devLoadI(rl) < ph + 1) __builtin_amdgcn_s_sleep(12);
        }
    }
    __syncthreads();
    asm volatile("" ::: "memory");
}

// ---------------- LDS union (max member = GEMM 48.5 KB; 3 blocks/CU) --------
union ShU {
    struct { float W1s[ICH][HIDC]; float xs[GEB][XS_PAD]; } g;        // 48.5KB
    struct { int shHist[SEL_BINS]; int aux[256]; int shTmp[2];
             int shS[SCAN_BS]; int preA[PRE_N]; int preB[PRE_N];
             int preC[PRE_N]; } m;                                    // ~19KB
    struct { float ring[2][64][HIDC]; int doneCnt[2]; int freeTok[2]; } r; // 32KB
};

struct FParams {
    // inputs
    const int* ei; const float* x; const float* W1; const float* b1;
    const float* gamma1; const float* beta1; const float* W2; const float* b2;
    const int* batch;
    // scratch
    int* cnt; int* bucketV; int* bucketS; int* ucnt; int* uoff; int* bsumsH;
    int* eU; int* eV; int* icnt; int* itmp; int* ilist; int* ilistS;
    float* dinv; float* h; float* Snode; float* partial; float* partial2;
    float* miniP; float* z; float* S2; float* score;
    u64* okey; u64* minOkey; int* hist;
    int* n2c; int* present; int* csize; int* cmemb;
    int* o2n; int* ni; int* ecnt2; int* etmp2; int* eoff2;
    int* uecnt; int* ueoff; int* bkD; int* bkD2;
    int* bsumsA; int* bsumsB; int* bsumsC;
    float* dout;
    int* sub; int* mid; int* fin; int* ep; int* relay;
};

// in-kernel exclusive scan, phase A (blocks 0..78); consumers rebuild the
// 79-entry block prefix in LDS (integer-exact == baseline scanA+scanB).
__device__ __forceinline__ void scanAPhase(const int* in, int* rawOut, int* bsums,
                                           int b, int t, int* shS) {
    if (b >= NSCAN_B) return;            // block-uniform branch
    int i = b * SCAN_BS + t;
    int v = (i < NND) ? in[i] : 0;
    shS[t] = v;
    __syncthreads();
    for (int o = 1; o < SCAN_BS; o <<= 1) {
        int tv = (t >= o) ? shS[t - o] : 0;
        __syncthreads();
        shS[t] += tv;
        __syncthreads();
    }
    if (i <= NND) devStoreI(rawOut + i, shS[t] - v);
    if (t == SCAN_BS - 1) devStoreI(bsums + b, shS[t]);
}
__device__ __forceinline__ void buildPre(const int* bsums, int* pre, int t) {
    if (t < NSCAN_B) pre[t + 1] = bsums[t];
    if (t == 0) pre[0] = 0;
    __syncthreads();
    if (t == 0)
        for (int k = 1; k <= NSCAN_B; k++) pre[k] += pre[k - 1];
    __syncthreads();
}
__device__ __forceinline__ int scanAt(const int* raw, const int* pre, int i) {
    return raw[i] + pre[i >> 8];         // valid for 0 <= i <= NND
}

// one radix-select q-step (12 bits); carried (pref, kr) across phases makes
// the baseline's full replay unnecessary -- integer-identical results.
__device__ __forceinline__ void selStep(const int* hq, int t, int* aux, int* shTmp,
                                        u64& pref, int& kr, int shift) {
    int b16[16]; int g = 0;
#pragma unroll
    for (int j = 0; j < 16; j++) { b16[j] = hq[16 * t + j]; g += b16[j]; }
    aux[t] = g;
    __syncthreads();
    for (int o = 1; o < 256; o <<= 1) {
        int v = (t + o < 256) ? aux[t + o] : 0;
        __syncthreads();
        aux[t] += v;
        __syncthreads();
    }
    int suf = aux[t] - g;
    if (suf < kr && kr <= suf + g) {
        int cum = suf, found = 16 * t;
        for (int j = 15; j >= 0; j--) {
            int hc = b16[j];
            if (cum + hc >= kr) { found = 16 * t + j; break; }
            cum += hc;
        }
        shTmp[0] = found;
        shTmp[1] = kr - cum;
    }
    __syncthreads();
    pref |= ((u64)shTmp[0]) << shift;
    kr = shTmp[1];
    __syncthreads();
}

// wave-parallel rank sort over stride-64 buckets (grid-stride, 4 waves/block)
__device__ __forceinline__ void rs64Phase(const int* in, int* out,
                                          const int* lenA, int* ucnt,
                                          int b, int w, int c) {
    for (int a = b * 4 + w; a < NND; a += FBLK * 4) {
        int len = lenA[a];
        int base = a << 6;
        for (int j = c; j < len; j += 64) {
            int v = in[base + j];
            int r = 0;
            for (int i = 0; i < len; i++) {
                int wv = in[base + i];
                r += (wv < v) || (wv == v && i < j);
            }
            devStoreI(out + base + r, v);
        }
        asm volatile("s_waitcnt vmcnt(0)" ::: "memory");
        int cc = 0;
        for (int j = c; j < len; j += 64)
            cc += (j == 0) || (out[base + j] != out[base + j - 1]);
#pragma unroll
        for (int o = 32; o > 0; o >>= 1) cc += __shfl_down(cc, o, 64);
        if (c == 0) devStoreI(ucnt + a, cc);
    }
}

__global__ __launch_bounds__(256, 3) void kFusedAll(FParams P) {
    __shared__ ShU sh;
    int t = threadIdx.x;
    int b = blockIdx.x;
    int gtid = b * 256 + t;
    int w = t >> 6, c = t & 63;
    int ph = 0;
    int E = 0;
#define GSYNC() do { gsync(P.sub, P.mid, P.fin, P.ep, P.relay, b, ph); ph++; } while (0)

    // ======== HEAD ========
    // ---- C1: filter (s<d) -> stride-64 buckets ----
    for (int i = gtid; i < EUA; i += FBLK * 256) {
        int s = P.ei[i], d = P.ei[EUA + i];
        if (s < d) {
            int p = atomicAdd(&P.cnt[s], 1);
            devStoreI(P.bucketV + (s << 6) + p, d);
        }
    }
    GSYNC();

    // ---- C2: rank-sort buckets + unique count ----
    rs64Phase(P.bucketV, P.bucketS, P.cnt, P.ucnt, b, w, c);
    GSYNC();

    // ---- C3: scanA(ucnt) -> uoffRaw, bsumsH ----
    scanAPhase(P.ucnt, P.uoff, P.bsumsH, b, t, sh.m.shS);
    GSYNC();

    // ---- C4: compact + incidence count + ilist scatter (C5 folded in;
    //      ilist order irrelevant -- rank-sorted to ilistS afterwards) ----
    buildPre(P.bsumsH, sh.m.preA, t);
    E = sh.m.preA[NSCAN_B];
    if (gtid < NND) {
        int u = gtid;
        int s = u << 6, e = s + P.cnt[u];
        int o = scanAt(P.uoff, sh.m.preA, u);
        int myc = 0;
        for (int i = s; i < e; i++)
            if (i == s || P.bucketS[i] != P.bucketS[i - 1]) {
                int v = P.bucketS[i];
                devStoreI(P.eU + o, u);
                devStoreI(P.eV + o, v);
                devStoreI(P.ilist + (u << 6) + atomicAdd(&P.itmp[u], 1), o);
                devStoreI(P.ilist + (v << 6) + atomicAdd(&P.itmp[v], 1), o);
                atomicAdd(&P.icnt[v], 1);
                o++;
                myc++;
            }
        if (myc) atomicAdd(&P.icnt[u], myc);
    }
    GSYNC();

    // ---- C6: dinv + GEMM h = (0.5*(x[u]+x[v])) @ W1 + rank-sort(ilist) ----
    for (int i = gtid; i < E; i += FBLK * 256)
        devStoreF(P.dinv + i,
                  rsqrtf((float)(P.icnt[P.eU[i]] + P.icnt[P.eV[i]] - 1)));
    {
        const float4* Wv = (const float4*)P.W1;
        float4* Ws = (float4*)&sh.g.W1s[0][0];
        for (int i = t; i < ICH * HIDC / 4; i += 256) Ws[i] = Wv[i];
        int nTiles = (E + GEB - 1) / GEB;
        for (int tile = b; tile < nTiles; tile += FBLK) {
            int e0 = tile * GEB;
            __syncthreads();
            {
                int eb = t >> 3, q = t & 7;   // 32 edges x 8 threads
                int e = e0 + eb;
                if (e < E) {
                    int u = P.eU[e], v = P.eV[e];
                    const float4* xu = (const float4*)(P.x + (size_t)u * ICH) + q * 4;
                    const float4* xv = (const float4*)(P.x + (size_t)v * ICH) + q * 4;
                    float* xd = &sh.g.xs[eb][q * 16];
#pragma unroll
                    for (int i = 0; i < 4; i++) {
                        float4 a = xu[i], bb = xv[i];
                        xd[i * 4 + 0] = 0.5f * (a.x + bb.x);
                        xd[i * 4 + 1] = 0.5f * (a.y + bb.y);
                        xd[i * 4 + 2] = 0.5f * (a.z + bb.z);
                        xd[i * 4 + 3] = 0.5f * (a.w + bb.w);
                    }
                }
            }
            __syncthreads();
            int cg4 = (t & 15) * 4;
            int es = t >> 4;                  // 0..15 -> edges es, es+16
            float a00=0,a01=0,a02=0,a03=0, a10=0,a11=0,a12=0,a13=0;
#pragma unroll 4
            for (int k = 0; k < ICH; k++) {
                float4 wv = *(const float4*)&sh.g.W1s[k][cg4];
                float x0 = sh.g.xs[es][k], x1 = sh.g.xs[es + 16][k];
                a00 += x0*wv.x; a01 += x0*wv.y; a02 += x0*wv.z; a03 += x0*wv.w;
                a10 += x1*wv.x; a11 += x1*wv.y; a12 += x1*wv.z; a13 += x1*wv.w;
            }
            int e;
            e = e0 + es;      if (e < E) devStoreF4(&P.h[(size_t)e*HIDC + cg4], a00,a01,a02,a03);
            e = e0 + es + 16; if (e < E) devStoreF4(&P.h[(size_t)e*HIDC + cg4], a10,a11,a12,a13);
        }
    }
    rs64Phase(P.ilist, P.ilistS, P.icnt, P.ucnt, b, w, c);  // ucnt = dummy
    GSYNC();

    // ======== MID-CHAIN ========
    // ---- phase 0: Snode[n][c] (== kSGather) ----
    for (int id = gtid; id < NND * HIDC; id += FBLK * 256) {
        int n = id >> 6;
        int base = n << 6, len = P.icnt[n];
        float acc = 0.f;
        for (int j = 0; j < len; j++) {
            int ed = P.ilistS[base + j];
            acc += P.h[(size_t)ed * HIDC + c] * P.dinv[ed];
        }
        devStoreF(P.Snode + id, acc);
    }
    GSYNC();

    // ---- phase 1: conv1 epilogue in regs + per-chain moments ----
    // chains live on blocks 0..511 only (layout frozen: bitwise == baseline)
    int gw = b * 4 + w;
    int cA = 2 * gw, cB = cA + 1;
    float vA[VMAX], vB[VMAX];
    if (b < 512) {
        float bc = P.b1[c];
        float accA = 0.f, acc2A = 0.f, accB = 0.f, acc2B = 0.f;
#pragma unroll
        for (int it = 0; it < VMAX; it++) {
            int eA = cA + it * CHAINS;
            if (eA < E) {
                float a = P.dinv[eA];
                float val = a * (P.Snode[(size_t)P.eU[eA] * HIDC + c] +
                                 P.Snode[(size_t)P.eV[eA] * HIDC + c]) -
                            a * a * P.h[(size_t)eA * HIDC + c] + bc;
                vA[it] = val; accA += val; acc2A += val * val;
            } else vA[it] = 0.f;
            int eB = cB + it * CHAINS;
            if (eB < E) {
                float a = P.dinv[eB];
                float val = a * (P.Snode[(size_t)P.eU[eB] * HIDC + c] +
                                 P.Snode[(size_t)P.eV[eB] * HIDC + c]) -
                            a * a * P.h[(size_t)eB * HIDC + c] + bc;
                vB[it] = val; accB += val; acc2B += val * val;
            } else vB[it] = 0.f;
        }
        devStoreF(P.partial  + cA * HIDC + c, accA);
        devStoreF(P.partial2 + cA * HIDC + c, acc2A);
        devStoreF(P.partial  + cB * HIDC + c, accB);
        devStoreF(P.partial2 + cB * HIDC + c, acc2B);
    }
    GSYNC();

    // ---- phase 2: quarter-sequential combine (bitwise == baseline kRed2),
    //      producer-consumer: waves 1-3 stream 64-row chunks into an LDS
    //      ring, wave 0 runs the SAME sequential 1024-add chain from LDS ----
    if (b < 8) {
        int q = b & 3;
        const float* src = ((b & 4) ? P.partial2 : P.partial) +
                           (size_t)q * (CHAINS / 4) * HIDC;
        if (t == 0) {
            sh.r.doneCnt[0] = 0; sh.r.doneCnt[1] = 0;
            sh.r.freeTok[0] = 0; sh.r.freeTok[1] = 1;
        }
        __syncthreads();
        if (w == 0) {            // consumer: lane c, channel c
            float acc = 0.f;
            for (int ch = 0; ch < 16; ch++) {
                int slot = ch & 1;
                int need = 192 * ((ch >> 1) + 1);
                while (__atomic_load_n(&sh.r.doneCnt[slot], __ATOMIC_RELAXED) < need)
                    ;
                const float* rg = &sh.r.ring[slot][0][0];
                for (int r = 0; r < 64; r++) acc += rg[r * HIDC + c];
                asm volatile("s_waitcnt lgkmcnt(0)" ::: "memory");
                __atomic_store_n(&sh.r.freeTok[slot], ch + 2, __ATOMIC_RELAXED);
            }
            devStoreF(P.miniP + b * HIDC + c, acc);
        } else {                 // producers: 192 threads
            int p = t - 64;
            for (int ch = 0; ch < 16; ch++) {
                int slot = ch & 1;
                while (__atomic_load_n(&sh.r.freeTok[slot], __ATOMIC_RELAXED) < ch)
                    ;
                const float* sbase = src + (size_t)(ch * 64) * HIDC;
                for (int idx = p; idx < 64 * 16; idx += 192) {
                    int row = idx >> 4, c4 = (idx & 15) << 2;
                    float4 v = *(const float4*)(sbase + row * HIDC + c4);
                    *(float4*)&sh.r.ring[slot][row][c4] = v;
                }
                asm volatile("s_waitcnt vmcnt(0) lgkmcnt(0)" ::: "memory");
                __atomic_fetch_add(&sh.r.doneCnt[slot], 1, __ATOMIC_RELAXED);
            }
        }
    }
    GSYNC();

    // ---- phase 3: replicated mu/var + batchnorm + relu + dot(W2) -> z ----
    if (b < 512) {
        float Ef = (float)E;
        float mu = (((P.miniP[0 * HIDC + c] + P.miniP[1 * HIDC + c]) +
                     P.miniP[2 * HIDC + c]) + P.miniP[3 * HIDC + c]) / Ef;
        float m2 = (((P.miniP[4 * HIDC + c] + P.miniP[5 * HIDC + c]) +
                     P.miniP[6 * HIDC + c]) + P.miniP[7 * HIDC + c]) / Ef;
        float rs = rsqrtf(m2 - mu * mu + 1e-5f);
        float gc = P.gamma1[c], be = P.beta1[c], wc = P.W2[c];
#pragma unroll
        for (int it = 0; it < VMAX; it++) {
            int eA = cA + it * CHAINS;
            if (eA < E) {
                float tt = gc * (vA[it] - mu) * rs + be;
                tt = tt > 0.f ? tt : 0.f;
                float p = tt * wc;
#pragma unroll
                for (int o = 32; o > 0; o >>= 1) p += __shfl_down(p, o, 64);
                if (c == 0) devStoreF(P.z + eA, p);
            }
            int eB = cB + it * CHAINS;
            if (eB < E) {
                float tt = gc * (vB[it] - mu) * rs + be;
                tt = tt > 0.f ? tt : 0.f;
                float p = tt * wc;
#pragma unroll
                for (int o = 32; o > 0; o >>= 1) p += __shfl_down(p, o, 64);
                if (c == 0) devStoreF(P.z + eB, p);
            }
        }
    }
    GSYNC();

    // ---- phase 4: S2 per node + minOkey init ----
    if (gtid < NND) {
        int base = gtid << 6, len = P.icnt[gtid];
        float a3 = 0.f;
        for (int j = 0; j < len; j++) {
            int e = P.ilistS[base + j];
            a3 += P.z[e] * P.dinv[e];
        }
        devStoreF(P.S2 + gtid, a3);
        devStoreU64(P.minOkey + gtid, ~0ULL);
    }
    GSYNC();

    // ---- phase 5: scores + 49-bit keys + radix pass-0 histogram ----
    for (int j = t; j < SEL_BINS; j += 256) sh.m.shHist[j] = 0;
    __syncthreads();
    if (gtid < E) {
        float a = P.dinv[gtid];
        float l = a * (P.S2[P.eU[gtid]] + P.S2[P.eV[gtid]]) - a * a * P.z[gtid] +
                  P.b2[0];
        float s = 1.f / (1.f + expf(-l));
        devStoreF(P.score + gtid, s);
        u32 bb = __float_as_uint(s);
        bb = (bb >> 31) ? ~bb : (bb | 0x80000000u);
        u64 key = (((u64)bb) << 17) | (u32)(0x1FFFFu - (u32)gtid);
        devStoreU64(P.okey + gtid, key);
        atomicAdd(&sh.m.shHist[(int)((key >> 36) & (SEL_BINS - 1))], 1);
    }
    __syncthreads();
    for (int j = t; j < SEL_BINS; j += 256) {
        int vv = sh.m.shHist[j];
        if (vv) atomicAdd(&P.hist[j], vv);
    }
    GSYNC();

    // ---- phases 6..8: radix passes 1..3 with register-carried (pref,kr) ----
    int kr = E / 2;
    if (kr > NND / 2) kr = NND / 2;
    if (kr < 1) kr = 1;
    u64 pref = 1ULL << 48;
    for (int pass = 1; pass < 4; pass++) {
        selStep(P.hist + (pass - 1) * SEL_BINS, t, sh.m.aux, sh.m.shTmp,
                pref, kr, 36 - 12 * (pass - 1));
        for (int j = t; j < SEL_BINS; j += 256) sh.m.shHist[j] = 0;
        __syncthreads();
        int shift = 36 - 12 * pass;
        u64 maskHi = (~0ULL) << (shift + 12);
        if (gtid < E) {
            u64 kk = P.okey[gtid];
            if ((kk & maskHi) == pref)
                atomicAdd(&sh.m.shHist[(int)((kk >> shift) & (SEL_BINS - 1))], 1);
        }
        __syncthreads();
        int* hp = P.hist + pass * SEL_BINS;
        for (int j = t; j < SEL_BINS; j += 256) {
            int vv = sh.m.shHist[j];
            if (vv) atomicAdd(&hp[j], vv);
        }
        GSYNC();
    }

    // ---- phase 9: final digit + per-dst min over selected keys ----
    selStep(P.hist + 3 * SEL_BINS, t, sh.m.aux, sh.m.shTmp, pref, kr, 0);
    if (gtid < E) {
        u64 k = P.okey[gtid];
        if (k >= pref) atomicMin(&P.minOkey[P.eV[gtid]], k);
    }
    GSYNC();

    // ---- phase 10: cluster assignment + member scatter ----
    if (gtid < NND) {
        u64 mk = P.minOkey[gtid];
        int m = gtid;
        if (mk != ~0ULL) m = P.eU[0x1FFFFu - (u32)(mk & 0x1FFFFu)];
        devStoreI(P.n2c + gtid, m);
        devStoreI(P.present + m, 1);
        int slot = atomicAdd(&P.csize[m], 1);
        devStoreI(P.cmemb + (m << 6) + slot, gtid);
    }
    GSYNC();

    // ======== TAIL ========
    // ---- T1: scanA(present) ----
    scanAPhase(P.present, P.o2n, P.bsumsA, b, t, sh.m.shS);
    GSYNC();

    // ---- T2: pooled features + pooled-edge count + ni ----
    buildPre(P.bsumsA, sh.m.preA, t);
    for (int i = gtid; i < EUA; i += FBLK * 256) {
        int a2 = scanAt(P.o2n, sh.m.preA, P.n2c[P.ei[i]]);
        int b2 = scanAt(P.o2n, sh.m.preA, P.n2c[P.ei[EUA + i]]);
        if (a2 != b2) atomicAdd(&P.ecnt2[a2], 1);
    }
    {
        int slot = t >> 7;
        int cc = t & 127;
        for (int u = b * 2 + slot; u < NND; u += FBLK * 2) {
            if (cc == 0) devStoreI(P.ni + u, scanAt(P.o2n, sh.m.preA, P.n2c[u]));
            if (P.present[u]) {
                int s = P.csize[u];
                int base2 = u << 6;
                float acc = 0.f;
                for (int j = 0; j < s; j++)
                    acc += P.x[(size_t)P.cmemb[base2 + j] * ICH + cc];
                P.dout[(size_t)scanAt(P.o2n, sh.m.preA, u) * ICH + cc] =
                    acc / (float)s;
            }
        }
    }
    GSYNC();

    // ---- T3: scanA(ecnt2) ----
    scanAPhase(P.ecnt2, P.eoff2, P.bsumsB, b, t, sh.m.shS);
    GSYNC();

    // ---- T4: pooled-edge scatter ----
    buildPre(P.bsumsB, sh.m.preB, t);
    for (int i = gtid; i < EUA; i += FBLK * 256) {
        int a2 = P.ni[P.ei[i]], b2 = P.ni[P.ei[EUA + i]];
        if (a2 != b2) {
            int p2 = scanAt(P.eoff2, sh.m.preB, a2) + atomicAdd(&P.etmp2[a2], 1);
            devStoreI(P.bkD + p2, b2);
        }
    }
    GSYNC();

    // ---- T5: per-wave rank sort of pooled buckets ----
    for (int a2 = b * 4 + w; a2 < NND; a2 += FBLK * 4) {
        int s = scanAt(P.eoff2, sh.m.preB, a2);
        int eE = scanAt(P.eoff2, sh.m.preB, a2 + 1);
        int len = eE - s;
        for (int j = c; j < len; j += 64) {
            int vv = P.bkD[s + j];
            int r = 0;
            for (int i = 0; i < len; i++) {
                int ww = P.bkD[s + i];
                r += (ww < vv) || (ww == vv && i < j);
            }
            devStoreI(P.bkD2 + s + r, vv);
        }
        asm volatile("s_waitcnt vmcnt(0)" ::: "memory");
        int cc2 = 0;
        for (int j = c; j < len; j += 64)
            cc2 += (j == 0) || (P.bkD2[s + j] != P.bkD2[s + j - 1]);
#pragma unroll
        for (int o = 32; o > 0; o >>= 1) cc2 += __shfl_down(cc2, o, 64);
        if (c == 0) devStoreI(P.uecnt + a2, cc2);
    }
    GSYNC();

    // ---- T6: scanA(uecnt) ----
    scanAPhase(P.uecnt, P.ueoff, P.bsumsC, b, t, sh.m.shS);
    GSYNC();

    // ---- T7: pooled-edge write + batch_pool + scores + ni ----
    {
        buildPre(P.bsumsC, sh.m.preC, t);
        int M = sh.m.preA[NSCAN_B], Ep = sh.m.preC[NSCAN_B];
        size_t base3 = (size_t)M * ICH;
        int bound = (E > NND) ? E : NND;
        for (int i = gtid; i < bound; i += FBLK * 256) {
            if (i < NND) {
                int s = scanAt(P.eoff2, sh.m.preB, i);
                int e2 = scanAt(P.eoff2, sh.m.preB, i + 1);
                float* r0 = P.dout + base3;
                float* r1 = r0 + Ep;
                int o = scanAt(P.ueoff, sh.m.preC, i);
                int prev = 0;
                for (int j = s; j < e2; j++) {
                    // bkD2 lines straddle bucket boundaries -> sc1 read
                    int bj = devLoadI(P.bkD2 + j);
                    if (j == s || bj != prev) {
                        r0[o] = (float)i;
                        r1[o] = (float)bj;
                        o++;
                    }
                    prev = bj;
                }
            }
            size_t tb = base3 + 2 * (size_t)Ep;
            if (i < NND && P.present[i])
                P.dout[tb + scanAt(P.o2n, sh.m.preA, i)] = (float)P.batch[i];
            if (i < E) P.dout[tb + M + i] = P.score[i];
            if (i < NND) P.dout[tb + M + E + i] = (float)P.ni[i];
        }
    }
#undef GSYNC
}

extern "C" void kernel_launch(void* const* d_in, const int* in_sizes, int n_in,
                              void* d_out, int out_size, void* d_ws, size_t ws_size,
                              hipStream_t stream) {
    (void)in_sizes; (void)n_in; (void)ws_size; (void)out_size;
    const float* x = (const float*)d_in[0];
    const float* W1 = (const float*)d_in[1];
    const float* b1 = (const float*)d_in[2];
    const float* gamma1 = (const float*)d_in[3];
    const float* beta1 = (const float*)d_in[4];
    const float* W2 = (const float*)d_in[5];
    const float* b2 = (const float*)d_in[6];
    const int* ei = (const int*)d_in[7];
    const int* batch = (const int*)d_in[8];
    float* dout = (float*)d_out;

    char* w = (char*)d_ws;
    size_t off = 0;
    auto carve = [&](size_t bytes) -> void* {
        off = (off + 255) & ~(size_t)255;
        void* p = w + off;
        off += bytes;
        return p;
    };
    // ---- contiguous zero-init region (ONE memset) ----
    char* zero0 = w;
    int* cnt = (int*)carve(NND * 4);
    int* itmp = (int*)carve(NND * 4);
    int* icnt = (int*)carve(NND * 4);
    int* present = (int*)carve(NND * 4);
    int* csize = (int*)carve(NND * 4);
    int* ecnt2 = (int*)carve(NND * 4);
    int* etmp2 = (int*)carve(NND * 4);
    int* hist4 = (int*)carve((size_t)4 * SEL_BINS * 4);
    int* sub = (int*)carve(NGRP * 16 * 4);           // arrival sub-lines
    int* midc = (int*)carve(8 * 16 * 4);             // mid-level lines
    int* fin = (int*)carve(16 * 4);                  // final counter
    int* ep = (int*)carve(16 * 4);                   // published epoch
    int* relay = (int*)carve(8 * 16 * 4);            // relay fan-out lines
    size_t zeroBytes = off;
    // ---- rest ----
    int* ucnt = (int*)carve(NND * 4);
    int* uoff = (int*)carve((NND + 2) * 4);
    int* bsumsH = (int*)carve((NSCAN_B + 2) * 4);
    int* bsumsA = (int*)carve((NSCAN_B + 2) * 4);
    int* bsumsB = (int*)carve((NSCAN_B + 2) * 4);
    int* bsumsC = (int*)carve((NSCAN_B + 2) * 4);
    int* n2c = (int*)carve(NND * 4);
    int* o2n = (int*)carve((NND + 2) * 4);
    int* niArr = (int*)carve(NND * 4);
    int* eoff2 = (int*)carve((NND + 2) * 4);
    int* uecnt = (int*)carve(NND * 4);
    int* ueoff = (int*)carve((NND + 2) * 4);
    int* bucketV = (int*)carve((size_t)NND * BK64 * 4);
    int* bucketS = (int*)carve((size_t)NND * BK64 * 4);
    int* cmemb = (int*)carve((size_t)NND * BK64 * 4);
    int* eU = (int*)carve(EFE * 4);
    int* eV = (int*)carve(EFE * 4);
    int* ilist = (int*)carve((size_t)NND * BK64 * 4);
    int* ilistS = (int*)carve((size_t)NND * BK64 * 4);
    int* bkD = (int*)carve(EUA * 4);
    int* bkD2 = (int*)carve(EUA * 4);
    u64* okey = (u64*)carve(EFE * 8);
    u64* minOkey = (u64*)carve(NND * 8);
    float* dinv = (float*)carve(EFE * 4);
    float* h = (float*)carve((size_t)EFE * HIDC * 4);
    float* Snode = (float*)carve((size_t)NND * HIDC * 4);
    float* partial = (float*)carve((size_t)CHAINS * HIDC * 4);
    float* partial2 = (float*)carve((size_t)CHAINS * HIDC * 4);
    float* miniP = (float*)carve(8 * HIDC * 4);
    float* zArr = (float*)carve(EFE * 4);
    float* S2 = (float*)carve(NND * 4);
    float* score = (float*)carve(EFE * 4);

    // zero scratch (one small memset; MUST cover barrier counters pre-launch)
    hipMemsetAsync(zero0, 0, zeroBytes, stream);

    FParams fp;
    fp.ei = ei; fp.x = x; fp.W1 = W1; fp.b1 = b1; fp.gamma1 = gamma1;
    fp.beta1 = beta1; fp.W2 = W2; fp.b2 = b2; fp.batch = batch;
    fp.cnt = cnt; fp.bucketV = bucketV; fp.bucketS = bucketS; fp.ucnt = ucnt;
    fp.uoff = uoff; fp.bsumsH = bsumsH;
    fp.eU = eU; fp.eV = eV; fp.icnt = icnt; fp.itmp = itmp;
    fp.ilist = ilist; fp.ilistS = ilistS;
    fp.dinv = dinv; fp.h = h; fp.Snode = Snode;
    fp.partial = partial; fp.partial2 = partial2; fp.miniP = miniP;
    fp.z = zArr; fp.S2 = S2; fp.score = score;
    fp.okey = okey; fp.minOkey = minOkey; fp.hist = hist4;
    fp.n2c = n2c; fp.present = present; fp.csize = csize; fp.cmemb = cmemb;
    fp.o2n = o2n; fp.ni = niArr; fp.ecnt2 = ecnt2; fp.etmp2 = etmp2;
    fp.eoff2 = eoff2; fp.uecnt = uecnt; fp.ueoff = ueoff;
    fp.bkD = bkD; fp.bkD2 = bkD2;
    fp.bsumsA = bsumsA; fp.bsumsB = bsumsB; fp.bsumsC = bsumsC;
    fp.dout = dout;
    fp.sub = sub; fp.mid = midc; fp.fin = fin; fp.ep = ep; fp.relay = relay;
    kFusedAll<<<FBLK, 256, 0, stream>>>(fp);
}

// Round 9
// 382.092 us; speedup vs baseline: 1.7153x; 1.3181x over previous
//
#include <hip/hip_runtime.h>
#include <stdint.h>

typedef unsigned long long u64;
typedef unsigned int u32;

#define NND 20000      // nodes
#define EUA 160000     // directed input edges (2 * E_UND)
#define EFE 80000      // max clean (undirected, deduped) edges
#define ICH 128
#define HIDC 64
#define SCAN_BS 256
#define NB_N ((NND + 255) / 256)
#define NB_EU ((EUA + 255) / 256)
#define NB_EF ((EFE + 255) / 256)
#define NB_E64 ((EFE * HIDC + 255) / 256)
#define NSCAN_B ((NND + SCAN_BS - 1) / SCAN_BS)   // 79
#define PRE_N (NSCAN_B + 1)                       // 80
#define HIST_BLOCKS 128
#define GEB 64         // edges per gemm block
#define GEMM_BLKS ((EFE + GEB - 1) / GEB)         // 1250
#define SORT_BLKS 1250 // rank-sort blocks appended to the gemm dispatch
#define XS_PAD 132     // xs leading-dim pad
#define NCHAIN 4096    // mean/var reduction chains (frozen: bitwise order)
#define BK64 64        // fixed bucket stride
#define SEL_BINS 4096  // 12-bit digits, 4 passes (keys: bit48==1 always)

// scal slots: 0=E, 2=M, 3=Ep, 15=dummy

// ---------------- scan phase A only (exclusive within block) ----------------
// Writes raw block-local exclusive scan (incl. index NND), per-block sums,
// and atomically accumulates the grand total. kScanB is GONE: consumers
// rebuild the 79-entry block prefix in LDS (integer-exact vs baseline).
__global__ void kScanA2(const int* __restrict__ in, int* __restrict__ out,
                        int* __restrict__ bsums, int* __restrict__ totalDst) {
    __shared__ int sh[SCAN_BS];
    int tid = threadIdx.x;
    int i = blockIdx.x * SCAN_BS + tid;
    int v = (i < NND) ? in[i] : 0;
    sh[tid] = v;
    __syncthreads();
    for (int o = 1; o < SCAN_BS; o <<= 1) {
        int t = (tid >= o) ? sh[tid - o] : 0;
        __syncthreads();
        sh[tid] += t;
        __syncthreads();
    }
    if (i <= NND) out[i] = sh[tid] - v;
    if (tid == SCAN_BS - 1) {
        bsums[blockIdx.x] = sh[tid];
        atomicAdd(totalDst, sh[tid]);
    }
}
// build 79-entry block prefix in LDS (works for blockDim 64..256)
__device__ __forceinline__ void buildPre(const int* __restrict__ bsums,
                                         int* pre, int t, int nthr) {
    for (int k = t; k < NSCAN_B; k += nthr) pre[k + 1] = bsums[k];
    if (t == 0) pre[0] = 0;
    __syncthreads();
    if (t == 0)
        for (int k = 1; k <= NSCAN_B; k++) pre[k] += pre[k - 1];
    __syncthreads();
}
__device__ __forceinline__ int scanAt(const int* __restrict__ raw,
                                      const int* pre, int i) {
    return raw[i] + pre[i >> 8];         // valid for 0 <= i <= NND
}

// ---------------- clean edge build (stride-64 direct buckets) ----------------
__global__ void kFilterScatter64(const int* __restrict__ ei, int* __restrict__ cnt,
                                 int* __restrict__ bucketV) {
    int i = blockIdx.x * 256 + threadIdx.x;
    if (i >= EUA) return;
    int s = ei[i], d = ei[EUA + i];
    if (s < d) {
        int p = atomicAdd(&cnt[s], 1);
        bucketV[(s << 6) + p] = d;
    }
}
// wave-parallel rank sort per fixed-stride bucket + unique count
__global__ void kRankSort64(const int* __restrict__ in, int* __restrict__ out,
                            const int* __restrict__ lenA, int* __restrict__ ucnt) {
    int a = blockIdx.x;
    int len = lenA[a];
    int base = a << 6;
    for (int j = threadIdx.x; j < len; j += 64) {
        int v = in[base + j];
        int r = 0;
        for (int i = 0; i < len; i++) {
            int w = in[base + i];
            r += (w < v) || (w == v && i < j);
        }
        out[base + r] = v;
    }
    __syncthreads();
    int c = 0;
    for (int j = threadIdx.x; j < len; j += 64)
        c += (j == 0) || (out[base + j] != out[base + j - 1]);
#pragma unroll
    for (int o = 32; o > 0; o >>= 1) c += __shfl_down(c, o, 64);
    if (threadIdx.x == 0) ucnt[a] = c;
}
// compact + incidence count + ilist scatter (old kIncScatterDinv's scatter
// folded in; ilist order irrelevant -- rank-sorted later). buildPre replaces
// the scanB pass. [proven in fused round 8]
__global__ void kCompactInc2(const int* __restrict__ arr, const int* __restrict__ cnt,
                             const int* __restrict__ uoffRaw,
                             const int* __restrict__ bsumsH,
                             int* __restrict__ eU, int* __restrict__ eV,
                             int* __restrict__ icnt, int* __restrict__ itmp,
                             int* __restrict__ ilist) {
    __shared__ int pre[PRE_N];
    int t = threadIdx.x;
    buildPre(bsumsH, pre, t, 256);
    int u = blockIdx.x * 256 + t;
    if (u >= NND) return;
    int s = u << 6, e = s + cnt[u];
    int o = scanAt(uoffRaw, pre, u);
    int myc = 0;
    for (int i = s; i < e; i++)
        if (i == s || arr[i] != arr[i - 1]) {
            int v = arr[i];
            eU[o] = u; eV[o] = v;
            ilist[(u << 6) + atomicAdd(&itmp[u], 1)] = o;
            ilist[(v << 6) + atomicAdd(&itmp[v], 1)] = o;
            atomicAdd(&icnt[v], 1);
            o++; myc++;
        }
    if (myc) atomicAdd(&icnt[u], myc);
}

// ---------------- GEMM + dinv + ilist rank-sort, one dispatch ---------------
// Blocks [0, GEMM_BLKS): dinv prologue + h = (0.5*(x[u]+x[v])) @ W1.
// Blocks [GEMM_BLKS, GEMM_BLKS+SORT_BLKS): 4 waves rank-sort ilist buckets.
// Independent data; the latency-bound sort overlaps the compute-bound GEMM.
__global__ void kGemmSort(const float* __restrict__ x, const float* __restrict__ W1,
                          const int* __restrict__ eU, const int* __restrict__ eV,
                          const int* __restrict__ scal, const int* __restrict__ icnt,
                          float* __restrict__ dinv, float* __restrict__ h,
                          const int* __restrict__ ilist, int* __restrict__ ilistS) {
    __shared__ float W1s[ICH][HIDC];
    __shared__ float xs[GEB][XS_PAD];
    int t = threadIdx.x;
    int E = scal[0];
    if (blockIdx.x >= GEMM_BLKS) {
        // rank-sort ilist buckets (ucnt not needed)
        int w = t >> 6, c = t & 63;
        for (int a = (blockIdx.x - GEMM_BLKS) * 4 + w; a < NND; a += SORT_BLKS * 4) {
            int len = icnt[a];
            int base = a << 6;
            for (int j = c; j < len; j += 64) {
                int v = ilist[base + j];
                int r = 0;
                for (int i = 0; i < len; i++) {
                    int wv = ilist[base + i];
                    r += (wv < v) || (wv == v && i < j);
                }
                ilistS[base + r] = v;
            }
        }
        return;
    }
    {   // dinv prologue (GEMM_BLKS*256 = 320000 >= E)
        int gid = blockIdx.x * 256 + t;
        if (gid < E)
            dinv[gid] = rsqrtf((float)(icnt[eU[gid]] + icnt[eV[gid]] - 1));
    }
    int e0 = blockIdx.x * GEB;
    if (e0 >= E) return;
    {
        const float4* Wv = (const float4*)W1;
        float4* Ws = (float4*)&W1s[0][0];
        for (int i = t; i < ICH * HIDC / 4; i += 256) Ws[i] = Wv[i];
    }
    {
        int eb = t >> 2, q = t & 3;
        int e = e0 + eb;
        if (e < E) {
            int u = eU[e], v = eV[e];
            const float4* xu = (const float4*)(x + (size_t)u * ICH) + q * 8;
            const float4* xv = (const float4*)(x + (size_t)v * ICH) + q * 8;
            float* xd = &xs[eb][q * 32];
#pragma unroll
            for (int i = 0; i < 8; i++) {
                float4 a = xu[i], b = xv[i];
                xd[i * 4 + 0] = 0.5f * (a.x + b.x);
                xd[i * 4 + 1] = 0.5f * (a.y + b.y);
                xd[i * 4 + 2] = 0.5f * (a.z + b.z);
                xd[i * 4 + 3] = 0.5f * (a.w + b.w);
            }
        }
    }
    __syncthreads();

    int cg4 = (t & 15) * 4;
    int es = t >> 4;
    float a00=0,a01=0,a02=0,a03=0, a10=0,a11=0,a12=0,a13=0;
    float a20=0,a21=0,a22=0,a23=0, a30=0,a31=0,a32=0,a33=0;
#pragma unroll 4
    for (int k = 0; k < ICH; k++) {
        float4 wv = *(const float4*)&W1s[k][cg4];
        float x0 = xs[es][k], x1 = xs[es + 16][k];
        float x2 = xs[es + 32][k], x3 = xs[es + 48][k];
        a00 += x0 * wv.x; a01 += x0 * wv.y; a02 += x0 * wv.z; a03 += x0 * wv.w;
        a10 += x1 * wv.x; a11 += x1 * wv.y; a12 += x1 * wv.z; a13 += x1 * wv.w;
        a20 += x2 * wv.x; a21 += x2 * wv.y; a22 += x2 * wv.z; a23 += x2 * wv.w;
        a30 += x3 * wv.x; a31 += x3 * wv.y; a32 += x3 * wv.z; a33 += x3 * wv.w;
    }
    int e;
    e = e0 + es;
    if (e < E) *(float4*)&h[(size_t)e * HIDC + cg4] = make_float4(a00, a01, a02, a03);
    e = e0 + es + 16;
    if (e < E) *(float4*)&h[(size_t)e * HIDC + cg4] = make_float4(a10, a11, a12, a13);
    e = e0 + es + 32;
    if (e < E) *(float4*)&h[(size_t)e * HIDC + cg4] = make_float4(a20, a21, a22, a23);
    e = e0 + es + 48;
    if (e < E) *(float4*)&h[(size_t)e * HIDC + cg4] = make_float4(a30, a31, a32, a33);
}

// S[n][c] = sum over incident edges (stride-64 list, sorted ascending)
__global__ void kSGather(const float* __restrict__ h, const float* __restrict__ dinv,
                         const int* __restrict__ icnt, const int* __restrict__ ilist,
                         float* __restrict__ S) {
    int n = blockIdx.x;
    int c = threadIdx.x;
    int base = n << 6, len = icnt[n];
    float acc = 0.f;
    for (int j = 0; j < len; j++) {
        int ed = ilist[base + j];
        acc += h[(size_t)ed * HIDC + c] * dinv[ed];
    }
    S[(size_t)n * HIDC + c] = acc;
}
// conv1 epilogue fused with ONE-PASS moment reduction (baseline, frozen)
__global__ void kConv1Red1(const float* __restrict__ h, const float* __restrict__ S,
                           const float* __restrict__ dinv, const int* __restrict__ eU,
                           const int* __restrict__ eV, const float* __restrict__ b1,
                           const int* __restrict__ scal, float* __restrict__ h2,
                           float* __restrict__ partial, float* __restrict__ partial2) {
    int t = threadIdx.x;
    int g = blockIdx.x * 4 + (t >> 6);
    int c = t & 63;
    int E = scal[0];
    float bc = b1[c];
    float acc = 0.f, acc2 = 0.f;
    for (int e = g; e < E; e += NCHAIN) {
        float a = dinv[e];
        float v = a * (S[(size_t)eU[e] * HIDC + c] + S[(size_t)eV[e] * HIDC + c]) -
                  a * a * h[(size_t)e * HIDC + c] + bc;
        h2[(size_t)e * HIDC + c] = v;
        acc += v;
        acc2 += v * v;
    }
    partial[g * HIDC + c] = acc;
    partial2[g * HIDC + c] = acc2;
}
// parallel kRed2: 8 blocks, quarter-sequential combine (bitwise == baseline
// kRed2's per-quarter order). Producer-consumer LDS ring [proven r5-r8]:
// waves 1-3 stream 64-row chunks; wave 0 runs the sequential 1024-add chain.
__global__ void kRed2a(const float* __restrict__ partial,
                       const float* __restrict__ partial2,
                       float* __restrict__ miniP) {
    __shared__ float ring[2][64][HIDC];
    __shared__ int doneCnt[2];
    __shared__ int freeTok[2];
    int t = threadIdx.x, b = blockIdx.x;
    int w = t >> 6, c = t & 63;
    int q = b & 3;
    const float* src = ((b & 4) ? partial2 : partial) +
                       (size_t)q * (NCHAIN / 4) * HIDC;
    if (t == 0) { doneCnt[0] = 0; doneCnt[1] = 0; freeTok[0] = 0; freeTok[1] = 1; }
    __syncthreads();
    if (w == 0) {                // consumer: lane c = channel c
        float acc = 0.f;
        for (int ch = 0; ch < 16; ch++) {
            int slot = ch & 1;
            int need = 192 * ((ch >> 1) + 1);
            while (__atomic_load_n(&doneCnt[slot], __ATOMIC_RELAXED) < need)
                ;
            const float* rg = &ring[slot][0][0];
            for (int r = 0; r < 64; r++) acc += rg[r * HIDC + c];
            asm volatile("s_waitcnt lgkmcnt(0)" ::: "memory");
            __atomic_store_n(&freeTok[slot], ch + 2, __ATOMIC_RELAXED);
        }
        miniP[b * HIDC + c] = acc;
    } else {                     // producers: 192 threads
        int p = t - 64;
        for (int ch = 0; ch < 16; ch++) {
            int slot = ch & 1;
            while (__atomic_load_n(&freeTok[slot], __ATOMIC_RELAXED) < ch)
                ;
            const float* sbase = src + (size_t)(ch * 64) * HIDC;
            for (int idx = p; idx < 64 * 16; idx += 192) {
                int row = idx >> 4, c4 = (idx & 15) << 2;
                float4 v = *(const float4*)(sbase + row * HIDC + c4);
                *(float4*)&ring[slot][row][c4] = v;
            }
            asm volatile("s_waitcnt vmcnt(0) lgkmcnt(0)" ::: "memory");
            __atomic_fetch_add(&doneCnt[slot], 1, __ATOMIC_RELAXED);
        }
    }
}
// fused batchnorm+relu+dot(W2); mu/var finished inline from miniP (bitwise ==
// baseline: (((m0+m1)+m2)+m3)/Ef, var = m2 - mu*mu, then +1e-5f).
__global__ void kNormZ2(const float* __restrict__ h2, const float* __restrict__ miniP,
                        const float* __restrict__ gamma1, const float* __restrict__ beta1,
                        const float* __restrict__ W2, const int* __restrict__ scal,
                        float* __restrict__ z) {
    int idx = blockIdx.x * 256 + threadIdx.x;
    int e = idx >> 6;
    if (e >= scal[0]) return;
    int c = idx & 63;
    float Ef = (float)scal[0];
    float mu = (((miniP[0 * HIDC + c] + miniP[1 * HIDC + c]) +
                 miniP[2 * HIDC + c]) + miniP[3 * HIDC + c]) / Ef;
    float m2 = (((miniP[4 * HIDC + c] + miniP[5 * HIDC + c]) +
                 miniP[6 * HIDC + c]) + miniP[7 * HIDC + c]) / Ef;
    float t = gamma1[c] * (h2[idx] - mu) * rsqrtf(m2 - mu * mu + 1e-5f) + beta1[c];
    t = t > 0.f ? t : 0.f;
    float p = t * W2[c];
#pragma unroll
    for (int o = 32; o > 0; o >>= 1) p += __shfl_down(p, o, 64);
    if (c == 0) z[e] = p;
}
__global__ void kS2(const float* __restrict__ z, const float* __restrict__ dinv,
                    const int* __restrict__ icnt, const int* __restrict__ ilist,
                    float* __restrict__ S2) {
    int n = blockIdx.x * 256 + threadIdx.x;
    if (n >= NND) return;
    int base = n << 6, len = icnt[n];
    float acc = 0.f;
    for (int j = 0; j < len; j++) {
        int e = ilist[base + j];
        acc += z[e] * dinv[e];
    }
    S2[n] = acc;
}
// scores + 49-bit keys + minOkey init + radix pass-0 histogram (baseline)
__global__ void kScore(const float* __restrict__ z, const float* __restrict__ S2,
                       const float* __restrict__ dinv, const int* __restrict__ eU,
                       const int* __restrict__ eV, const float* __restrict__ b2,
                       const int* __restrict__ scal, float* __restrict__ score,
                       u64* __restrict__ okey, u64* __restrict__ minOkey,
                       int* __restrict__ hist0) {
    __shared__ int sh[SEL_BINS];
    int t = threadIdx.x;
    for (int j = t; j < SEL_BINS; j += 256) sh[j] = 0;
    __syncthreads();
    int e = blockIdx.x * 256 + t;
    if (e < NND) minOkey[e] = ~0ULL;
    int E = scal[0];
    if (e < E) {
        float a = dinv[e];
        float l = a * (S2[eU[e]] + S2[eV[e]]) - a * a * z[e] + b2[0];
        float s = 1.f / (1.f + expf(-l));
        score[e] = s;
        u32 b = __float_as_uint(s);
        b = (b >> 31) ? ~b : (b | 0x80000000u);
        u64 key = (((u64)b) << 17) | (u32)(0x1FFFFu - (u32)e);
        okey[e] = key;
        atomicAdd(&sh[(int)((key >> 36) & (SEL_BINS - 1))], 1);
    }
    __syncthreads();
    for (int j = t; j < SEL_BINS; j += 256) {
        int v = sh[j];
        if (v) atomicAdd(&hist0[j], v);
    }
}

// ---------------- radix select: replay-based (baseline) ---------------------
__device__ __forceinline__ u64 selReplay(const int* __restrict__ histBase, int passes,
                                         int E, int t, int* aux, int* shTmp) {
    int kr = E / 2;
    if (kr > NND / 2) kr = NND / 2;
    if (kr < 1) kr = 1;
    u64 pref = 1ULL << 48;
    for (int q = 0; q < passes; q++) {
        int shift = 36 - 12 * q;
        const int* hq = histBase + q * SEL_BINS;
        int b[16];
        int g = 0;
#pragma unroll
        for (int j = 0; j < 16; j++) { b[j] = hq[16 * t + j]; g += b[j]; }
        aux[t] = g;
        __syncthreads();
        for (int o = 1; o < 256; o <<= 1) {
            int v = (t + o < 256) ? aux[t + o] : 0;
            __syncthreads();
            aux[t] += v;
            __syncthreads();
        }
        int suf = aux[t] - g;  // strictly-above my 16-bin group
        if (suf < kr && kr <= suf + g) {
            int cum = suf, found = 16 * t;
            for (int j = 15; j >= 0; j--) {
                int hc = b[j];
                if (cum + hc >= kr) { found = 16 * t + j; break; }
                cum += hc;
            }
            shTmp[0] = found;
            shTmp[1] = kr - cum;
        }
        __syncthreads();
        pref |= ((u64)shTmp[0]) << shift;
        kr = shTmp[1];
        __syncthreads();
    }
    return pref;
}
__global__ void kHistR(const u64* __restrict__ okey, const int* __restrict__ scal,
                       int* __restrict__ histBase, int pass) {
    __shared__ int sh[4][SEL_BINS];   // 64 KB: 4 per-wave sub-hists
    __shared__ int aux[256];
    __shared__ int shTmp[2];
    int t = threadIdx.x;
    int E = scal[0];
    u64 p = selReplay(histBase, pass, E, t, aux, shTmp);
    for (int j = t; j < 4 * SEL_BINS; j += 256) ((int*)sh)[j] = 0;
    __syncthreads();
    int wv = t >> 6;
    int shift = 36 - 12 * pass;
    u64 maskHi = (~0ULL) << (shift + 12);
    for (int e = blockIdx.x * 256 + t; e < E; e += HIST_BLOCKS * 256) {
        u64 kk = okey[e];
        if ((kk & maskHi) == p)
            atomicAdd(&sh[wv][(int)((kk >> shift) & (SEL_BINS - 1))], 1);
    }
    __syncthreads();
    int* hp = histBase + pass * SEL_BINS;
    for (int j = t; j < SEL_BINS; j += 256) {
        int v = sh[0][j] + sh[1][j] + sh[2][j] + sh[3][j];
        if (v) atomicAdd(&hp[j], v);
    }
}
__global__ void kMinKey(const u64* __restrict__ okey, const int* __restrict__ eV,
                        const int* __restrict__ scal, const int* __restrict__ histBase,
                        u64* __restrict__ minOkey) {
    __shared__ int aux[256];
    __shared__ int shTmp[2];
    int t = threadIdx.x;
    int E = scal[0];
    u64 pref = selReplay(histBase, 4, E, t, aux, shTmp);
    int i = blockIdx.x * 256 + t;
    if (i < E) {
        u64 k = okey[i];
        if (k >= pref) atomicMin(&minOkey[eV[i]], k);
    }
}
__global__ void kCluster(const u64* __restrict__ minOkey, const int* __restrict__ eU,
                         int* __restrict__ n2c, int* __restrict__ present,
                         int* __restrict__ csize, int* __restrict__ cmemb) {
    int v = blockIdx.x * 256 + threadIdx.x;
    if (v >= NND) return;
    u64 mk = minOkey[v];
    int m = v;
    if (mk != ~0ULL) m = eU[0x1FFFFu - (u32)(mk & 0x1FFFFu)];
    n2c[v] = m;
    present[m] = 1;
    int slot = atomicAdd(&csize[m], 1);
    cmemb[(m << 6) + slot] = v;
}

// ---------------- pooled features + pooled-edge count (buildPre o2n) --------
__global__ void kXPoolCE2(const float* __restrict__ x, const int* __restrict__ n2c,
                          const int* __restrict__ o2nRaw, const int* __restrict__ bsumsA,
                          const int* __restrict__ present, const int* __restrict__ csize,
                          const int* __restrict__ cmemb, const int* __restrict__ ei,
                          int* __restrict__ ni, float* __restrict__ dout,
                          int* __restrict__ ecnt2) {
    __shared__ int pre[PRE_N];
    int u = blockIdx.x;
    int c = threadIdx.x;
    buildPre(bsumsA, pre, c, 128);
    int gid = u * 128 + c;
    if (gid < EUA) {
        int a = scanAt(o2nRaw, pre, n2c[ei[gid]]);
        int b = scanAt(o2nRaw, pre, n2c[ei[EUA + gid]]);
        if (a != b) atomicAdd(&ecnt2[a], 1);
    }
    if (c == 0) ni[u] = scanAt(o2nRaw, pre, n2c[u]);
    if (!present[u]) return;
    int s = csize[u];
    int base = u << 6;
    float acc = 0.f;
    for (int j = 0; j < s; j++)
        acc += x[(size_t)cmemb[base + j] * ICH + c];
    dout[(size_t)scanAt(o2nRaw, pre, u) * ICH + c] = acc / (float)s;
}

// ---------------- pooled edges ----------------
__global__ void kCEscatter2(const int* __restrict__ ei, const int* __restrict__ ni,
                            const int* __restrict__ eoff2Raw,
                            const int* __restrict__ bsumsB,
                            int* __restrict__ etmp2, int* __restrict__ bkD) {
    __shared__ int pre[PRE_N];
    int t = threadIdx.x;
    buildPre(bsumsB, pre, t, 256);
    int i = blockIdx.x * 256 + t;
    if (i >= EUA) return;
    int a = ni[ei[i]], b = ni[ei[EUA + i]];
    if (a != b) {
        int p = scanAt(eoff2Raw, pre, a) + atomicAdd(&etmp2[a], 1);
        bkD[p] = b;
    }
}
// variable-offset rank sort (pooled-edge buckets; buildPre for offsets)
__global__ void kRankSort2(const int* __restrict__ in, int* __restrict__ out,
                           const int* __restrict__ eoff2Raw,
                           const int* __restrict__ bsumsB, int* __restrict__ ucnt) {
    __shared__ int pre[PRE_N];
    int t = threadIdx.x;
    buildPre(bsumsB, pre, t, 64);
    int a = blockIdx.x;
    int s = scanAt(eoff2Raw, pre, a), e = scanAt(eoff2Raw, pre, a + 1);
    int len = e - s;
    for (int j = t; j < len; j += 64) {
        int v = in[s + j];
        int r = 0;
        for (int i = 0; i < len; i++) {
            int w = in[s + i];
            r += (w < v) || (w == v && i < j);
        }
        out[s + r] = v;
    }
    __syncthreads();
    int c = 0;
    for (int j = t; j < len; j += 64)
        c += (j == 0) || (out[s + j] != out[s + j - 1]);
#pragma unroll
    for (int o = 32; o > 0; o >>= 1) c += __shfl_down(c, o, 64);
    if (t == 0) ucnt[a] = c;
}
// pooled-edge write + batch_pool + scores + ni, one dispatch (3x buildPre)
__global__ void kCEwriteTail2(const int* __restrict__ bkD2,
                              const int* __restrict__ eoff2Raw,
                              const int* __restrict__ ueoffRaw,
                              const int* __restrict__ o2nRaw,
                              const int* __restrict__ bsumsA,
                              const int* __restrict__ bsumsB,
                              const int* __restrict__ bsumsC,
                              const int* __restrict__ scal,
                              const int* __restrict__ batch,
                              const int* __restrict__ present,
                              const float* __restrict__ score,
                              const int* __restrict__ ni, float* __restrict__ dout) {
    __shared__ int preA[PRE_N];
    __shared__ int preB[PRE_N];
    __shared__ int preC[PRE_N];
    int t = threadIdx.x;
    // build all three prefixes (manual: buildPre has syncthreads)
    for (int k = t; k < NSCAN_B; k += 256) {
        preA[k + 1] = bsumsA[k];
        preB[k + 1] = bsumsB[k];
        preC[k + 1] = bsumsC[k];
    }
    if (t == 0) { preA[0] = 0; preB[0] = 0; preC[0] = 0; }
    __syncthreads();
    if (t == 0)
        for (int k = 1; k <= NSCAN_B; k++) {
            preA[k] += preA[k - 1];
            preB[k] += preB[k - 1];
            preC[k] += preC[k - 1];
        }
    __syncthreads();
    int i = blockIdx.x * 256 + t;
    int E = scal[0], M = scal[2], Ep = scal[3];
    size_t base = (size_t)M * ICH;
    if (i < NND) {
        int s = scanAt(eoff2Raw, preB, i), e = scanAt(eoff2Raw, preB, i + 1);
        float* r0 = dout + base;
        float* r1 = r0 + Ep;
        int o = scanAt(ueoffRaw, preC, i);
        for (int j = s; j < e; j++)
            if (j == s || bkD2[j] != bkD2[j - 1]) {
                r0[o] = (float)i;
                r1[o] = (float)bkD2[j];
                o++;
            }
    }
    size_t tb = base + 2 * (size_t)Ep;
    if (i < NND && present[i]) dout[tb + scanAt(o2nRaw, preA, i)] = (float)batch[i];
    if (i < E) dout[tb + M + i] = score[i];
    if (i < NND) dout[tb + M + E + i] = (float)ni[i];
}

extern "C" void kernel_launch(void* const* d_in, const int* in_sizes, int n_in,
                              void* d_out, int out_size, void* d_ws, size_t ws_size,
                              hipStream_t stream) {
    (void)in_sizes; (void)n_in; (void)ws_size; (void)out_size;
    const float* x = (const float*)d_in[0];
    const float* W1 = (const float*)d_in[1];
    const float* b1 = (const float*)d_in[2];
    const float* gamma1 = (const float*)d_in[3];
    const float* beta1 = (const float*)d_in[4];
    const float* W2 = (const float*)d_in[5];
    const float* b2 = (const float*)d_in[6];
    const int* ei = (const int*)d_in[7];
    const int* batch = (const int*)d_in[8];
    float* dout = (float*)d_out;

    char* w = (char*)d_ws;
    size_t off = 0;
    auto carve = [&](size_t bytes) -> void* {
        off = (off + 255) & ~(size_t)255;
        void* p = w + off;
        off += bytes;
        return p;
    };
    // ---- contiguous zero-init region (ONE memset) ----
    char* zero0 = w;
    int* cnt = (int*)carve(NND * 4);
    int* itmp = (int*)carve(NND * 4);
    int* icnt = (int*)carve(NND * 4);
    int* present = (int*)carve(NND * 4);
    int* csize = (int*)carve(NND * 4);
    int* ecnt2 = (int*)carve(NND * 4);
    int* etmp2 = (int*)carve(NND * 4);
    int* scal = (int*)carve(16 * 4);
    int* hist4 = (int*)carve((size_t)4 * SEL_BINS * 4);
    size_t zeroBytes = off;
    // ---- rest ----
    int* ucnt = (int*)carve(NND * 4);
    int* uoff = (int*)carve((NND + 2) * 4);
    int* bsumsH = (int*)carve((NSCAN_B + 2) * 4);
    int* bsumsA = (int*)carve((NSCAN_B + 2) * 4);
    int* bsumsB = (int*)carve((NSCAN_B + 2) * 4);
    int* bsumsC = (int*)carve((NSCAN_B + 2) * 4);
    int* n2c = (int*)carve(NND * 4);
    int* o2n = (int*)carve((NND + 2) * 4);
    int* niArr = (int*)carve(NND * 4);
    int* eoff2 = (int*)carve((NND + 2) * 4);
    int* uecnt = (int*)carve(NND * 4);
    int* ueoff = (int*)carve((NND + 2) * 4);
    int* bucketV = (int*)carve((size_t)NND * BK64 * 4);  // later reused: cmemb
    int* bucketS = (int*)carve((size_t)NND * BK64 * 4);
    int* eU = (int*)carve(EFE * 4);
    int* eV = (int*)carve(EFE * 4);
    int* ilist = (int*)carve((size_t)NND * BK64 * 4);
    int* ilistS = (int*)carve((size_t)NND * BK64 * 4);
    int* bkD = (int*)carve(EUA * 4);
    int* bkD2 = (int*)carve(EUA * 4);
    u64* okey = (u64*)carve(EFE * 8);
    u64* minOkey = (u64*)carve(NND * 8);
    float* dinv = (float*)carve(EFE * 4);
    float* h = (float*)carve((size_t)EFE * HIDC * 4);
    float* h2 = (float*)carve((size_t)EFE * HIDC * 4);
    float* Snode = (float*)carve((size_t)NND * HIDC * 4);
    float* partial = (float*)carve((size_t)NCHAIN * HIDC * 4);
    float* partial2 = (float*)carve((size_t)NCHAIN * HIDC * 4);
    float* miniP = (float*)carve(8 * HIDC * 4);
    float* zArr = (float*)carve(EFE * 4);
    float* S2 = (float*)carve(NND * 4);
    float* score = (float*)carve(EFE * 4);

    // zero scratch (one memset; scal must be zeroed for the atomic totals)
    hipMemsetAsync(zero0, 0, zeroBytes, stream);

    // clean edge list: buckets -> rank-sort -> scanA -> compact(+ilist)
    kFilterScatter64<<<NB_EU, 256, 0, stream>>>(ei, cnt, bucketV);
    kRankSort64<<<NND, 64, 0, stream>>>(bucketV, bucketS, cnt, ucnt);
    kScanA2<<<NSCAN_B, SCAN_BS, 0, stream>>>(ucnt, uoff, bsumsH, scal + 0);
    kCompactInc2<<<NB_N, 256, 0, stream>>>(bucketS, cnt, uoff, bsumsH, eU, eV,
                                           icnt, itmp, ilist);

    // dinv + conv1 GEMM + ilist rank-sort (one dispatch, disjoint block sets)
    kGemmSort<<<GEMM_BLKS + SORT_BLKS, 256, 0, stream>>>(x, W1, eU, eV, scal,
                                                         icnt, dinv, h, ilist,
                                                         ilistS);

    // conv1 epilogue + moments (baseline) -> parallel combine -> norm+dot
    kSGather<<<NND, HIDC, 0, stream>>>(h, dinv, icnt, ilistS, Snode);
    kConv1Red1<<<NCHAIN / 4, 256, 0, stream>>>(h, Snode, dinv, eU, eV, b1, scal,
                                               h2, partial, partial2);
    kRed2a<<<8, 256, 0, stream>>>(partial, partial2, miniP);
    kNormZ2<<<NB_E64, 256, 0, stream>>>(h2, miniP, gamma1, beta1, W2, scal, zArr);

    // conv2 -> scores + keys (+minOkey init + select pass 0)
    kS2<<<NB_N, 256, 0, stream>>>(zArr, dinv, icnt, ilistS, S2);
    kScore<<<NB_EF, 256, 0, stream>>>(zArr, S2, dinv, eU, eV, b2, scal, score,
                                      okey, minOkey, hist4);

    // exact k-th largest: passes 1..3 (pass 0 folded into kScore)
    for (int p = 1; p < 4; p++)
        kHistR<<<HIST_BLOCKS, 256, 0, stream>>>(okey, scal, hist4, p);

    // cluster
    kMinKey<<<NB_EF, 256, 0, stream>>>(okey, eV, scal, hist4, minOkey);
    kCluster<<<NB_N, 256, 0, stream>>>(minOkey, eU, n2c, present, csize, bucketV);
    kScanA2<<<NSCAN_B, SCAN_BS, 0, stream>>>(present, o2n, bsumsA, scal + 2);

    // pooled features + pooled-edge count
    kXPoolCE2<<<NND, 128, 0, stream>>>(x, n2c, o2n, bsumsA, present, csize,
                                       bucketV, ei, niArr, dout, ecnt2);

    // pooled edges
    kScanA2<<<NSCAN_B, SCAN_BS, 0, stream>>>(ecnt2, eoff2, bsumsB, scal + 15);
    kCEscatter2<<<NB_EU, 256, 0, stream>>>(ei, niArr, eoff2, bsumsB, etmp2, bkD);
    kRankSort2<<<NND, 64, 0, stream>>>(bkD, bkD2, eoff2, bsumsB, uecnt);
    kScanA2<<<NSCAN_B, SCAN_BS, 0, stream>>>(uecnt, ueoff, bsumsC, scal + 3);
    kCEwriteTail2<<<NB_EF, 256, 0, stream>>>(bkD2, eoff2, ueoff, o2n, bsumsA,
                                             bsumsB, bsumsC, scal, batch, present,
                                             score, niArr, dout);
}